// Round 6
// baseline (874.556 us; speedup 1.0000x reference)
//
#include <hip/hip_runtime.h>

// Round 6: hoist x@Wx out of the serial loop.
// xw_gemm precomputes (x@Wx + bias*QS^2) for all (b,t) at full-GPU
// parallelism using the SAME fp8 quantization + mfma_scale as the proven
// persistent kernel, stores bf16 [T][B][U] (128 MB in ws). The persistent
// kernel then runs h@Wh only (16 MFMA/wave/step vs 20), with the xw value
// prefetched thread-locally from global one step ahead and used as the
// accumulator init (C-in of the first MFMA). Fallback to the round-5
// kernel when ws_size can't hold xwp.

typedef __attribute__((ext_vector_type(8))) int i32x8_t;
typedef __attribute__((ext_vector_type(4))) float f32x4_t;

constexpr int Bn = 256, Tn = 512, En = 100, Un = 512;
constexpr int D1n = 1024, D2n = 1024, Cn = 10;
constexpr float QS  = 256.f;               // quant scale 2^8
constexpr float INV = 1.52587890625e-05f;  // 2^-16
constexpr int USC = 0x7F7F7F7F;            // unit E8M0 scales (2^0)

// ---- fp8 e4m3fn conversion helpers ----------------------------------------
__device__ __forceinline__ unsigned f2e4m3_sw(float x) {
    unsigned u = __float_as_uint(x);
    unsigned sgn = (u >> 24) & 0x80;
    float a = __uint_as_float(u & 0x7FFFFFFF);
    if (a >= 448.f) return sgn | 0x7E;
    if (a < 0.015625f) {
        unsigned q = (unsigned)__float2int_rn(a * 512.f);
        return sgn | q;
    }
    int e = (int)((u >> 23) & 0xFF) - 127;
    unsigned m = u & 0x7FFFFF;
    unsigned mant = m >> 20, rem = m & 0xFFFFF;
    if (rem > 0x80000 || (rem == 0x80000 && (mant & 1))) {
        if (++mant == 8) { mant = 0; ++e; }
    }
    if (e > 8) return sgn | 0x7E;
    return sgn | ((unsigned)(e + 7) << 3) | mant;
}

__device__ __forceinline__ unsigned cvt1(float x) {
#if __has_builtin(__builtin_amdgcn_cvt_pk_fp8_f32)
    return (unsigned)__builtin_amdgcn_cvt_pk_fp8_f32(x, x, 0, false) & 0xFFu;
#else
    return f2e4m3_sw(x);
#endif
}

__device__ __forceinline__ unsigned pk4(float a, float b, float c, float d) {
#if __has_builtin(__builtin_amdgcn_cvt_pk_fp8_f32)
    int r = __builtin_amdgcn_cvt_pk_fp8_f32(a, b, 0, false);
    r = __builtin_amdgcn_cvt_pk_fp8_f32(c, d, r, true);
    return (unsigned)r;
#else
    return f2e4m3_sw(a) | (f2e4m3_sw(b) << 8) | (f2e4m3_sw(c) << 16) |
           (f2e4m3_sw(d) << 24);
#endif
}

__device__ __forceinline__ ushort f2bf(float x) {
    unsigned u = __float_as_uint(x);
    unsigned r = (u + 0x7FFFu + ((u >> 16) & 1u)) >> 16;   // RNE
    return (ushort)r;
}

// ---------------------------------------------------------------------------
// Pack Wh [512][512] f32 -> fp8 MX A-fragment order (scaled by QS).
// ---------------------------------------------------------------------------
__global__ __launch_bounds__(256) void pack_wh8(const float* __restrict__ Wh,
                                                unsigned char* __restrict__ P) {
    int e = blockIdx.x * 256 + threadIdx.x;          // < 262144
    int j = e & 31, l = (e >> 5) & 63, kc = (e >> 11) & 3, nt = e >> 13;
    int k = kc * 128 + (l >> 4) * 32 + j;
    int c = nt * 16 + (l & 15);
    P[e] = (unsigned char)cvt1(Wh[k * Un + c] * QS);
}

__global__ __launch_bounds__(256) void pack_wx8(const float* __restrict__ Wx,
                                                unsigned char* __restrict__ P) {
    int e = blockIdx.x * 256 + threadIdx.x;          // < 65536
    int j = e & 31, l = (e >> 5) & 63, nt = e >> 11;
    int k = (l >> 4) * 32 + j;
    int c = nt * 16 + (l & 15);
    P[e] = (k < En) ? (unsigned char)cvt1(Wx[k * Un + c] * QS) : 0;
}

// ---------------------------------------------------------------------------
// xw_gemm: xwp[t][b][u] = bf16( QS^2*(x_fp8 @ Wx_fp8) + b_rnn[u]*QS^2 )
// Grid (16 b-groups, 32 t-chunks of 16), 512 threads. Same fp8 quantization
// and MFMA path as the persistent kernel -> numerics identical to round 5.
// ---------------------------------------------------------------------------
__global__ __launch_bounds__(512) void xw_gemm(
    const int* __restrict__ tokens, const float* __restrict__ emb,
    const float* __restrict__ b_rnn, const unsigned char* __restrict__ WxP8,
    ushort* __restrict__ xwp)
{
    __shared__ char XS[32768];       // 16 slabs of [16 rows][128 k] fp8

    const int tid  = threadIdx.x;
    const int lane = tid & 63;
    const int wv   = tid >> 6;
    const int r0   = blockIdx.x * 16;
    const int t0   = blockIdx.y * 16;

    const int r16 = lane & 15;
    const int q   = lane >> 4;

    // gather x for 16 timesteps: 16 tt * 16 rows * 25 float4
    for (int idx = tid; idx < 6400; idx += 512) {
        int tt   = idx / 400;
        int rem  = idx - tt * 400;
        int prow = rem / 25;
        int pc4  = rem - prow * 25;
        int tok  = tokens[(r0 + prow) * Tn + t0 + tt];
        float4 v = *(const float4*)(emb + tok * En + pc4 * 4);
        *(unsigned*)(XS + tt * 2048 + ((prow * 128 + pc4 * 4) ^ (prow << 4))) =
            pk4(v.x * QS, v.y * QS, v.z * QS, v.w * QS);
    }
    // zero-pad k = 100..127 (7 dwords per row)
    for (int idx = tid; idx < 16 * 16 * 7; idx += 512) {
        int tt   = idx / 112;
        int rem  = idx - tt * 112;
        int prow = rem / 7;
        int c4   = 25 + (rem - prow * 7);
        *(unsigned*)(XS + tt * 2048 + ((prow * 128 + c4 * 4) ^ (prow << 4))) = 0;
    }
    __syncthreads();

    i32x8_t wxf[4];
#pragma unroll
    for (int p = 0; p < 4; ++p)
        wxf[p] = *(const i32x8_t*)(WxP8 + ((wv * 4 + p) * 64 + lane) * 32);

    float biasQ[4][4];
#pragma unroll
    for (int p = 0; p < 4; ++p)
#pragma unroll
        for (int j = 0; j < 4; ++j)
            biasQ[p][j] = b_rnn[(wv * 4 + p) * 16 + q * 4 + j] * 65536.f;

    const int bswz = r16 << 4;
    for (int tt = 0; tt < 16; ++tt) {
        const int xb = tt * 2048 + ((r16 * 128 + q * 32) ^ bswz);
        uint4 blo = *(const uint4*)(XS + xb);
        uint4 bhi = *(const uint4*)(XS + (tt * 2048 +
                        (((r16 * 128 + q * 32) + 16) ^ bswz)));
        i32x8_t bf = {(int)blo.x, (int)blo.y, (int)blo.z, (int)blo.w,
                      (int)bhi.x, (int)bhi.y, (int)bhi.z, (int)bhi.w};
        f32x4_t acc[4];
#pragma unroll
        for (int p = 0; p < 4; ++p) {
            acc[p] = (f32x4_t){biasQ[p][0], biasQ[p][1], biasQ[p][2], biasQ[p][3]};
            acc[p] = __builtin_amdgcn_mfma_scale_f32_16x16x128_f8f6f4(
                wxf[p], bf, acc[p], 0, 0, 0, USC, 0, USC);
        }
#pragma unroll
        for (int p = 0; p < 4; ++p) {
            int n = (wv * 4 + p) * 16 + q * 4;
            size_t base = ((size_t)(t0 + tt) * Bn + r0 + r16) * Un + n;
            unsigned u0 = (unsigned)f2bf(acc[p][0]) | ((unsigned)f2bf(acc[p][1]) << 16);
            unsigned u1 = (unsigned)f2bf(acc[p][2]) | ((unsigned)f2bf(acc[p][3]) << 16);
            *(uint2*)(xwp + base) = make_uint2(u0, u1);
        }
    }
}

// ---------------------------------------------------------------------------
// Slim persistent RNN (h@Wh only). LDS: H0@0(8192) H1@8192 TOK@16384(16KB).
// xw init prefetched from global 1 step ahead into registers.
// ---------------------------------------------------------------------------
__global__ __launch_bounds__(512, 2) void rnn_persist8x(
    const int* __restrict__ tokens, const unsigned char* __restrict__ WhP8,
    const ushort* __restrict__ xwp, float* __restrict__ h_final)
{
    __shared__ char sh[32768];
    char* H0 = sh;            char* H1 = sh + 8192;
    char* TOKB = sh + 16384;

    const int tid  = threadIdx.x;
    const int lane = tid & 63;
    const int wv   = tid >> 6;
    const int r0   = blockIdx.x * 16;

    const int r16  = lane & 15;
    const int q    = lane >> 4;
    const int bswz = r16 << 4;

    for (int f = tid; f < 16 * Tn; f += 512) {
        int row = f >> 9, tt = f & 511;
        *(ushort*)(TOKB + ((((row << 10) | (tt << 1))) ^ (row << 2))) =
            (ushort)tokens[r0 * Tn + f];
    }
    {   // zero H0
        int* z = (int*)sh;
        for (int f = tid; f < 2048; f += 512) z[f] = 0;
    }
    __syncthreads();

    i32x8_t whf[4][4];
#pragma unroll
    for (int kc = 0; kc < 4; ++kc)
#pragma unroll
        for (int p = 0; p < 4; ++p)
            whf[kc][p] = *(const i32x8_t*)(WhP8 +
                (((wv * 4 + p) * 4 + kc) * 64 + lane) * 32);

    // per-thread xw pointer: row r0+r16, cols wv*64 + q*4 (+p*16)
    const ushort* xwT = xwp + ((size_t)(r0 + r16) * Un + wv * 64 + q * 4);

    float hprev[4][4];
#pragma unroll
    for (int p = 0; p < 4; ++p)
#pragma unroll
        for (int j = 0; j < 4; ++j) hprev[p][j] = 0.f;

    uint2 pfA[4], pfB[4];
#pragma unroll
    for (int p = 0; p < 4; ++p)
        pfA[p] = *(const uint2*)(xwT + p * 16);

#define BFL(u) __uint_as_float((u) << 16)
#define BFH(u) __uint_as_float((u) & 0xFFFF0000u)

#define RNN_STEP(T, HC, HN, PFC, PFN)                                          \
    {                                                                          \
        const int t = (T);                                                     \
        if (t + 1 < Tn) {                                                      \
            const ushort* xt = xwT + (size_t)(t + 1) * (Bn * Un);              \
            _Pragma("unroll")                                                  \
            for (int p = 0; p < 4; ++p)                                        \
                PFN[p] = *(const uint2*)(xt + p * 16);                         \
        }                                                                      \
        f32x4_t acc[4];                                                        \
        _Pragma("unroll")                                                      \
        for (int p = 0; p < 4; ++p)                                            \
            acc[p] = (f32x4_t){BFL(PFC[p].x), BFH(PFC[p].x),                   \
                               BFL(PFC[p].y), BFH(PFC[p].y)};                  \
        _Pragma("unroll")                                                      \
        for (int kc = 0; kc < 4; ++kc) {                                       \
            const int bb = r16 * 512 + kc * 128 + q * 32;                      \
            uint4 blo = *(const uint4*)((HC) + ((bb) ^ bswz));                 \
            uint4 bhi = *(const uint4*)((HC) + ((bb + 16) ^ bswz));            \
            i32x8_t bf = {(int)blo.x, (int)blo.y, (int)blo.z, (int)blo.w,      \
                          (int)bhi.x, (int)bhi.y, (int)bhi.z, (int)bhi.w};     \
            _Pragma("unroll")                                                  \
            for (int p = 0; p < 4; ++p)                                        \
                acc[p] = __builtin_amdgcn_mfma_scale_f32_16x16x128_f8f6f4(     \
                    whf[kc][p], bf, acc[p], 0, 0, 0, USC, 0, USC);             \
        }                                                                      \
        const bool mk = *(const ushort*)(TOKB +                                \
            ((((r16 << 10) | (t << 1))) ^ (r16 << 2))) != 0;                   \
        _Pragma("unroll")                                                      \
        for (int p = 0; p < 4; ++p) {                                          \
            float v0 = fmaxf(acc[p][0] * INV, 0.f);                            \
            float v1 = fmaxf(acc[p][1] * INV, 0.f);                            \
            float v2 = fmaxf(acc[p][2] * INV, 0.f);                            \
            float v3 = fmaxf(acc[p][3] * INV, 0.f);                            \
            v0 = mk ? v0 : hprev[p][0];  v1 = mk ? v1 : hprev[p][1];           \
            v2 = mk ? v2 : hprev[p][2];  v3 = mk ? v3 : hprev[p][3];           \
            hprev[p][0] = v0; hprev[p][1] = v1;                                \
            hprev[p][2] = v2; hprev[p][3] = v3;                                \
            *(unsigned*)((HN) +                                                \
                ((r16 * 512 + (wv * 4 + p) * 16 + q * 4) ^ bswz)) =            \
                pk4(v0 * QS, v1 * QS, v2 * QS, v3 * QS);                       \
        }                                                                      \
        __syncthreads();                                                       \
    }

    for (int t2 = 0; t2 < Tn; t2 += 2) {
        RNN_STEP(t2,     H0, H1, pfA, pfB)
        RNN_STEP(t2 + 1, H1, H0, pfB, pfA)
    }
#undef RNN_STEP
#undef BFL
#undef BFH

#pragma unroll
    for (int p = 0; p < 4; ++p) {
        int n = (wv * 4 + p) * 16 + q * 4;
#pragma unroll
        for (int j = 0; j < 4; ++j)
            h_final[(r0 + r16) * Un + n + j] = hprev[p][j];
    }
}

// ---------------------------------------------------------------------------
// Fallback: round-5 persistent kernel (in-loop x@Wx), used when ws is small.
// ---------------------------------------------------------------------------
__global__ __launch_bounds__(512, 2) void rnn_persist8(
    const int* __restrict__ tokens, const float* __restrict__ emb,
    const float* __restrict__ b_rnn,
    const unsigned char* __restrict__ WhP8, const unsigned char* __restrict__ WxP8,
    float* __restrict__ h_final)
{
    __shared__ char sh[36864];
    char* H0 = sh;            char* H1 = sh + 8192;
    char* X0 = sh + 16384;    char* X1 = sh + 18432;
    char* TOKB = sh + 20480;

    const int tid  = threadIdx.x;
    const int lane = tid & 63;
    const int wv   = tid >> 6;
    const int r0   = blockIdx.x * 16;

    const int r16  = lane & 15;
    const int q    = lane >> 4;
    const int bswz = r16 << 4;

    for (int f = tid; f < 16 * Tn; f += 512) {
        int row = f >> 9, tt = f & 511;
        *(ushort*)(TOKB + ((((row << 10) | (tt << 1))) ^ (row << 2))) =
            (ushort)tokens[r0 * Tn + f];
    }
    {
        int* z = (int*)sh;
        for (int f = tid; f < 2048; f += 512) z[f] = 0;
        int* zx = (int*)(sh + 16384);
        for (int f = tid; f < 1024; f += 512) zx[f] = 0;
    }
    __syncthreads();

    i32x8_t whf[4][4], wxf[4];
#pragma unroll
    for (int kc = 0; kc < 4; ++kc)
#pragma unroll
        for (int p = 0; p < 4; ++p)
            whf[kc][p] = *(const i32x8_t*)(WhP8 +
                (((wv * 4 + p) * 4 + kc) * 64 + lane) * 32);
#pragma unroll
    for (int p = 0; p < 4; ++p)
        wxf[p] = *(const i32x8_t*)(WxP8 + ((wv * 4 + p) * 64 + lane) * 32);

    float bias_r[4][4];
#pragma unroll
    for (int p = 0; p < 4; ++p)
#pragma unroll
        for (int j = 0; j < 4; ++j)
            bias_r[p][j] = b_rnn[(wv * 4 + p) * 16 + q * 4 + j];

    const int prow = tid / 25;
    const int pc4  = tid - prow * 25;
    const bool is_pref = (tid < 400);
    const int pxaddr = (prow * 128 + pc4 * 4) ^ (prow << 4);

    if (is_pref) {
        int tk = (int)*(const ushort*)(TOKB + (((prow << 10)) ^ (prow << 2)));
        float4 v = *(const float4*)(emb + tk * En + pc4 * 4);
        *(unsigned*)(X0 + pxaddr) = pk4(v.x * QS, v.y * QS, v.z * QS, v.w * QS);
    }
    __syncthreads();

    float hprev[4][4];
#pragma unroll
    for (int p = 0; p < 4; ++p)
#pragma unroll
        for (int j = 0; j < 4; ++j) hprev[p][j] = 0.f;

#define RNN_STEP(T, HC, HN, XC, XN)                                            \
    {                                                                          \
        const int t = (T);                                                     \
        float4 pref;                                                           \
        const bool dp = is_pref && (t + 1 < Tn);                               \
        if (dp) {                                                              \
            int tk = (int)*(const ushort*)(TOKB +                              \
                ((((prow << 10) | ((t + 1) << 1))) ^ (prow << 2)));            \
            pref = *(const float4*)(emb + tk * En + pc4 * 4);                  \
        }                                                                      \
        f32x4_t acc[4];                                                        \
        _Pragma("unroll")                                                      \
        for (int p = 0; p < 4; ++p) acc[p] = (f32x4_t){0.f, 0.f, 0.f, 0.f};    \
        _Pragma("unroll")                                                      \
        for (int kc = 0; kc < 4; ++kc) {                                       \
            const int bb = r16 * 512 + kc * 128 + q * 32;                      \
            uint4 blo = *(const uint4*)((HC) + ((bb) ^ bswz));                 \
            uint4 bhi = *(const uint4*)((HC) + ((bb + 16) ^ bswz));            \
            i32x8_t bf = {(int)blo.x, (int)blo.y, (int)blo.z, (int)blo.w,      \
                          (int)bhi.x, (int)bhi.y, (int)bhi.z, (int)bhi.w};     \
            _Pragma("unroll")                                                  \
            for (int p = 0; p < 4; ++p)                                        \
                acc[p] = __builtin_amdgcn_mfma_scale_f32_16x16x128_f8f6f4(     \
                    whf[kc][p], bf, acc[p], 0, 0, 0, USC, 0, USC);             \
        }                                                                      \
        {                                                                      \
            const int xb = r16 * 128 + q * 32;                                 \
            uint4 blo = *(const uint4*)((XC) + ((xb) ^ bswz));                 \
            uint4 bhi = *(const uint4*)((XC) + ((xb + 16) ^ bswz));            \
            i32x8_t bf = {(int)blo.x, (int)blo.y, (int)blo.z, (int)blo.w,      \
                          (int)bhi.x, (int)bhi.y, (int)bhi.z, (int)bhi.w};     \
            _Pragma("unroll")                                                  \
            for (int p = 0; p < 4; ++p)                                        \
                acc[p] = __builtin_amdgcn_mfma_scale_f32_16x16x128_f8f6f4(     \
                    wxf[p], bf, acc[p], 0, 0, 0, USC, 0, USC);                 \
        }                                                                      \
        const bool mk = *(const ushort*)(TOKB +                                \
            ((((r16 << 10) | (t << 1))) ^ (r16 << 2))) != 0;                   \
        _Pragma("unroll")                                                      \
        for (int p = 0; p < 4; ++p) {                                          \
            float v0 = fmaxf(acc[p][0] * INV + bias_r[p][0], 0.f);             \
            float v1 = fmaxf(acc[p][1] * INV + bias_r[p][1], 0.f);             \
            float v2 = fmaxf(acc[p][2] * INV + bias_r[p][2], 0.f);             \
            float v3 = fmaxf(acc[p][3] * INV + bias_r[p][3], 0.f);             \
            v0 = mk ? v0 : hprev[p][0];  v1 = mk ? v1 : hprev[p][1];           \
            v2 = mk ? v2 : hprev[p][2];  v3 = mk ? v3 : hprev[p][3];           \
            hprev[p][0] = v0; hprev[p][1] = v1;                                \
            hprev[p][2] = v2; hprev[p][3] = v3;                                \
            *(unsigned*)((HN) +                                                \
                ((r16 * 512 + (wv * 4 + p) * 16 + q * 4) ^ bswz)) =            \
                pk4(v0 * QS, v1 * QS, v2 * QS, v3 * QS);                       \
        }                                                                      \
        if (dp) {                                                              \
            *(unsigned*)((XN) + pxaddr) =                                      \
                pk4(pref.x * QS, pref.y * QS, pref.z * QS, pref.w * QS);       \
        }                                                                      \
        __syncthreads();                                                       \
    }

    for (int t2 = 0; t2 < Tn; t2 += 2) {
        RNN_STEP(t2,     H0, H1, X0, X1)
        RNN_STEP(t2 + 1, H1, H0, X1, X0)
    }
#undef RNN_STEP

#pragma unroll
    for (int p = 0; p < 4; ++p) {
        int n = (wv * 4 + p) * 16 + q * 4;
#pragma unroll
        for (int j = 0; j < 4; ++j)
            h_final[(r0 + r16) * Un + n + j] = hprev[p][j];
    }
}

// ---------------------------------------------------------------------------
// MLP: 32-row tiles (halved W traffic), K staged in 512-chunks (64 KB LDS).
// ---------------------------------------------------------------------------
template <int K, bool RELU>
__global__ __launch_bounds__(256) void fc32(
    const float* __restrict__ in, const float* __restrict__ W,
    const float* __restrict__ b, float* __restrict__ out, int N)
{
    __shared__ float in_lds[32][512];
    const int tid = threadIdx.x;
    const int r0  = blockIdx.y * 32;
    const int c0  = blockIdx.x * 32;

    const int col = c0 + (tid & 31);
    const int rq  = (tid >> 5) * 4;     // 4 rows per thread

    float acc0 = b[col], acc1 = acc0, acc2 = acc0, acc3 = acc0;

    for (int kc = 0; kc < K / 512; ++kc) {
        if (kc) __syncthreads();
        for (int i = tid; i < 32 * 512; i += 256) {
            int r = i >> 9, c = i & 511;
            in_lds[r][c] = in[(r0 + r) * K + kc * 512 + c];
        }
        __syncthreads();

        const float4* v0 = (const float4*)(&in_lds[rq + 0][0]);
        const float4* v1 = (const float4*)(&in_lds[rq + 1][0]);
        const float4* v2 = (const float4*)(&in_lds[rq + 2][0]);
        const float4* v3 = (const float4*)(&in_lds[rq + 3][0]);
        for (int k4 = 0; k4 < 128; ++k4) {
            float4 a0 = v0[k4], a1 = v1[k4], a2 = v2[k4], a3 = v3[k4];
            int k = kc * 512 + k4 * 4;
            float w0 = W[(k + 0) * N + col];
            float w1 = W[(k + 1) * N + col];
            float w2 = W[(k + 2) * N + col];
            float w3 = W[(k + 3) * N + col];
            acc0 += a0.x * w0 + a0.y * w1 + a0.z * w2 + a0.w * w3;
            acc1 += a1.x * w0 + a1.y * w1 + a1.z * w2 + a1.w * w3;
            acc2 += a2.x * w0 + a2.y * w1 + a2.z * w2 + a2.w * w3;
            acc3 += a3.x * w0 + a3.y * w1 + a3.z * w2 + a3.w * w3;
        }
    }
    if (RELU) {
        acc0 = fmaxf(acc0, 0.f); acc1 = fmaxf(acc1, 0.f);
        acc2 = fmaxf(acc2, 0.f); acc3 = fmaxf(acc3, 0.f);
    }
    out[(r0 + rq + 0) * N + col] = acc0;
    out[(r0 + rq + 1) * N + col] = acc1;
    out[(r0 + rq + 2) * N + col] = acc2;
    out[(r0 + rq + 3) * N + col] = acc3;
}

__global__ __launch_bounds__(64) void head_softmax(
    const float* __restrict__ h2, const float* __restrict__ Wo,
    const float* __restrict__ bo, float* __restrict__ out)
{
    const int b    = blockIdx.x;
    const int lane = threadIdx.x;

    float acc[Cn];
#pragma unroll
    for (int c = 0; c < Cn; ++c) acc[c] = 0.f;

    for (int k = lane; k < D2n; k += 64) {
        float hv = h2[b * D2n + k];
#pragma unroll
        for (int c = 0; c < Cn; ++c) acc[c] += hv * Wo[k * Cn + c];
    }
#pragma unroll
    for (int c = 0; c < Cn; ++c) {
#pragma unroll
        for (int off = 32; off > 0; off >>= 1)
            acc[c] += __shfl_down(acc[c], off);
    }
    if (lane == 0) {
        float l[Cn], mx = -1e30f;
#pragma unroll
        for (int c = 0; c < Cn; ++c) { l[c] = acc[c] + bo[c]; mx = fmaxf(mx, l[c]); }
        float s = 0.f;
#pragma unroll
        for (int c = 0; c < Cn; ++c) { l[c] = __expf(l[c] - mx); s += l[c]; }
        float inv = 1.f / s;
#pragma unroll
        for (int c = 0; c < Cn; ++c) out[b * Cn + c] = l[c] * inv;
    }
}

extern "C" void kernel_launch(void* const* d_in, const int* in_sizes, int n_in,
                              void* d_out, int out_size, void* d_ws, size_t ws_size,
                              hipStream_t stream)
{
    const int*   tokens = (const int*)d_in[0];
    const float* emb    = (const float*)d_in[1];
    const float* Wx     = (const float*)d_in[2];
    const float* Wh     = (const float*)d_in[3];
    const float* b_rnn  = (const float*)d_in[4];
    const float* W1     = (const float*)d_in[5];
    const float* b1     = (const float*)d_in[6];
    const float* W2     = (const float*)d_in[7];
    const float* b2     = (const float*)d_in[8];
    const float* Wo     = (const float*)d_in[9];
    const float* bo     = (const float*)d_in[10];
    float* out = (float*)d_out;

    char* ws = (char*)d_ws;
    unsigned char* WhP8 = (unsigned char*)ws;                 // 256 KB
    unsigned char* WxP8 = (unsigned char*)(ws + (256 << 10)); // 64 KB
    float* h_last = (float*)(ws + (320 << 10));               // 512 KB
    float* h1     = (float*)(ws + (832 << 10));               // 1 MB
    float* h2     = (float*)(ws + (1856 << 10));              // 1 MB
    ushort* xwp   = (ushort*)(ws + (3u << 20));               // 128 MB
    const size_t need = (3u << 20) + (size_t)Tn * Bn * Un * sizeof(ushort);

    pack_wh8<<<1024, 256, 0, stream>>>(Wh, WhP8);
    pack_wx8<<<256, 256, 0, stream>>>(Wx, WxP8);

    if (ws_size >= need) {
        xw_gemm<<<dim3(16, 32), 512, 0, stream>>>(tokens, emb, b_rnn, WxP8, xwp);
        rnn_persist8x<<<Bn / 16, 512, 0, stream>>>(tokens, WhP8, xwp, h_last);
    } else {
        rnn_persist8<<<Bn / 16, 512, 0, stream>>>(
            tokens, emb, b_rnn, WhP8, WxP8, h_last);
    }

    dim3 bs(256);
    fc32<Un, true><<<dim3(D1n / 32, Bn / 32), bs, 0, stream>>>(h_last, W1, b1, h1, D1n);
    fc32<D1n, true><<<dim3(D2n / 32, Bn / 32), bs, 0, stream>>>(h1, W2, b2, h2, D2n);
    head_softmax<<<Bn, 64, 0, stream>>>(h2, Wo, bo, out);
}

// Round 7
// 611.392 us; speedup vs baseline: 1.4304x; 1.4304x over previous
//
#include <hip/hip_runtime.h>

// Round 7: fix the xw prefetch access pattern (round-6 regression root cause).
// xwp layout is now per-thread-contiguous [t][blk][tid][16 bf16 = 32B]:
// the persistent kernel's thread (wv,lane) needs exactly the 16 values that
// xw_gemm's identical thread computes (same MFMA D-layout), so both sides
// become 2x dwordx4 at tid-consecutive addresses (2KB contiguous per wave,
// ~16 transactions vs ~512/CU/step scattered before).

typedef __attribute__((ext_vector_type(8))) int i32x8_t;
typedef __attribute__((ext_vector_type(4))) float f32x4_t;

constexpr int Bn = 256, Tn = 512, En = 100, Un = 512;
constexpr int D1n = 1024, D2n = 1024, Cn = 10;
constexpr float QS  = 256.f;               // quant scale 2^8
constexpr float INV = 1.52587890625e-05f;  // 2^-16
constexpr int USC = 0x7F7F7F7F;            // unit E8M0 scales (2^0)
constexpr int XW_STEP = 16 * 512 * 16;     // ushorts per t-slice (256 KB)

// ---- fp8 e4m3fn conversion helpers ----------------------------------------
__device__ __forceinline__ unsigned f2e4m3_sw(float x) {
    unsigned u = __float_as_uint(x);
    unsigned sgn = (u >> 24) & 0x80;
    float a = __uint_as_float(u & 0x7FFFFFFF);
    if (a >= 448.f) return sgn | 0x7E;
    if (a < 0.015625f) {
        unsigned q = (unsigned)__float2int_rn(a * 512.f);
        return sgn | q;
    }
    int e = (int)((u >> 23) & 0xFF) - 127;
    unsigned m = u & 0x7FFFFF;
    unsigned mant = m >> 20, rem = m & 0xFFFFF;
    if (rem > 0x80000 || (rem == 0x80000 && (mant & 1))) {
        if (++mant == 8) { mant = 0; ++e; }
    }
    if (e > 8) return sgn | 0x7E;
    return sgn | ((unsigned)(e + 7) << 3) | mant;
}

__device__ __forceinline__ unsigned cvt1(float x) {
#if __has_builtin(__builtin_amdgcn_cvt_pk_fp8_f32)
    return (unsigned)__builtin_amdgcn_cvt_pk_fp8_f32(x, x, 0, false) & 0xFFu;
#else
    return f2e4m3_sw(x);
#endif
}

__device__ __forceinline__ unsigned pk4(float a, float b, float c, float d) {
#if __has_builtin(__builtin_amdgcn_cvt_pk_fp8_f32)
    int r = __builtin_amdgcn_cvt_pk_fp8_f32(a, b, 0, false);
    r = __builtin_amdgcn_cvt_pk_fp8_f32(c, d, r, true);
    return (unsigned)r;
#else
    return f2e4m3_sw(a) | (f2e4m3_sw(b) << 8) | (f2e4m3_sw(c) << 16) |
           (f2e4m3_sw(d) << 24);
#endif
}

__device__ __forceinline__ ushort f2bf(float x) {
    unsigned u = __float_as_uint(x);
    unsigned r = (u + 0x7FFFu + ((u >> 16) & 1u)) >> 16;   // RNE
    return (ushort)r;
}

// ---------------------------------------------------------------------------
// Pack Wh [512][512] f32 -> fp8 MX A-fragment order (scaled by QS).
// ---------------------------------------------------------------------------
__global__ __launch_bounds__(256) void pack_wh8(const float* __restrict__ Wh,
                                                unsigned char* __restrict__ P) {
    int e = blockIdx.x * 256 + threadIdx.x;          // < 262144
    int j = e & 31, l = (e >> 5) & 63, kc = (e >> 11) & 3, nt = e >> 13;
    int k = kc * 128 + (l >> 4) * 32 + j;
    int c = nt * 16 + (l & 15);
    P[e] = (unsigned char)cvt1(Wh[k * Un + c] * QS);
}

__global__ __launch_bounds__(256) void pack_wx8(const float* __restrict__ Wx,
                                                unsigned char* __restrict__ P) {
    int e = blockIdx.x * 256 + threadIdx.x;          // < 65536
    int j = e & 31, l = (e >> 5) & 63, nt = e >> 11;
    int k = (l >> 4) * 32 + j;
    int c = nt * 16 + (l & 15);
    P[e] = (k < En) ? (unsigned char)cvt1(Wx[k * Un + c] * QS) : 0;
}

// ---------------------------------------------------------------------------
// xw_gemm: computes bf16( QS^2*(x_fp8 @ Wx_fp8) + b_rnn*QS^2 ) and stores it
// per-thread-contiguous: xwp[((t*16+blk)*512 + tid)*16 .. +16).
// ---------------------------------------------------------------------------
__global__ __launch_bounds__(512) void xw_gemm(
    const int* __restrict__ tokens, const float* __restrict__ emb,
    const float* __restrict__ b_rnn, const unsigned char* __restrict__ WxP8,
    ushort* __restrict__ xwp)
{
    __shared__ char XS[32768];       // 16 slabs of [16 rows][128 k] fp8

    const int tid  = threadIdx.x;
    const int lane = tid & 63;
    const int wv   = tid >> 6;
    const int r0   = blockIdx.x * 16;
    const int t0   = blockIdx.y * 16;

    const int r16 = lane & 15;
    const int q   = lane >> 4;

    // gather x for 16 timesteps: 16 tt * 16 rows * 25 float4
    for (int idx = tid; idx < 6400; idx += 512) {
        int tt   = idx / 400;
        int rem  = idx - tt * 400;
        int prow = rem / 25;
        int pc4  = rem - prow * 25;
        int tok  = tokens[(r0 + prow) * Tn + t0 + tt];
        float4 v = *(const float4*)(emb + tok * En + pc4 * 4);
        *(unsigned*)(XS + tt * 2048 + ((prow * 128 + pc4 * 4) ^ (prow << 4))) =
            pk4(v.x * QS, v.y * QS, v.z * QS, v.w * QS);
    }
    // zero-pad k = 100..127 (7 dwords per row)
    for (int idx = tid; idx < 16 * 16 * 7; idx += 512) {
        int tt   = idx / 112;
        int rem  = idx - tt * 112;
        int prow = rem / 7;
        int c4   = 25 + (rem - prow * 7);
        *(unsigned*)(XS + tt * 2048 + ((prow * 128 + c4 * 4) ^ (prow << 4))) = 0;
    }
    __syncthreads();

    i32x8_t wxf[4];
#pragma unroll
    for (int p = 0; p < 4; ++p)
        wxf[p] = *(const i32x8_t*)(WxP8 + ((wv * 4 + p) * 64 + lane) * 32);

    float biasQ[4][4];
#pragma unroll
    for (int p = 0; p < 4; ++p)
#pragma unroll
        for (int j = 0; j < 4; ++j)
            biasQ[p][j] = b_rnn[(wv * 4 + p) * 16 + q * 4 + j] * 65536.f;

    const int bswz = r16 << 4;
    for (int tt = 0; tt < 16; ++tt) {
        uint4 blo = *(const uint4*)(XS + tt * 2048 +
                        ((r16 * 128 + q * 32) ^ bswz));
        uint4 bhi = *(const uint4*)(XS + tt * 2048 +
                        (((r16 * 128 + q * 32) + 16) ^ bswz));
        i32x8_t bf = {(int)blo.x, (int)blo.y, (int)blo.z, (int)blo.w,
                      (int)bhi.x, (int)bhi.y, (int)bhi.z, (int)bhi.w};
        f32x4_t acc[4];
#pragma unroll
        for (int p = 0; p < 4; ++p) {
            acc[p] = (f32x4_t){biasQ[p][0], biasQ[p][1], biasQ[p][2], biasQ[p][3]};
            acc[p] = __builtin_amdgcn_mfma_scale_f32_16x16x128_f8f6f4(
                wxf[p], bf, acc[p], 0, 0, 0, USC, 0, USC);
        }
        // per-thread-contiguous store (wave writes 2KB contiguous)
        size_t base = (((size_t)(t0 + tt) * 16 + blockIdx.x) * 512 + tid) * 16;
        uint4 lo, hi;
        lo.x = (unsigned)f2bf(acc[0][0]) | ((unsigned)f2bf(acc[0][1]) << 16);
        lo.y = (unsigned)f2bf(acc[0][2]) | ((unsigned)f2bf(acc[0][3]) << 16);
        lo.z = (unsigned)f2bf(acc[1][0]) | ((unsigned)f2bf(acc[1][1]) << 16);
        lo.w = (unsigned)f2bf(acc[1][2]) | ((unsigned)f2bf(acc[1][3]) << 16);
        hi.x = (unsigned)f2bf(acc[2][0]) | ((unsigned)f2bf(acc[2][1]) << 16);
        hi.y = (unsigned)f2bf(acc[2][2]) | ((unsigned)f2bf(acc[2][3]) << 16);
        hi.z = (unsigned)f2bf(acc[3][0]) | ((unsigned)f2bf(acc[3][1]) << 16);
        hi.w = (unsigned)f2bf(acc[3][2]) | ((unsigned)f2bf(acc[3][3]) << 16);
        *(uint4*)(xwp + base)     = lo;
        *(uint4*)(xwp + base + 8) = hi;
    }
}

// ---------------------------------------------------------------------------
// Slim persistent RNN (h@Wh only). LDS: H0@0(8192) H1@8192 TOK@16384(16KB).
// xw init prefetched thread-contiguously from global 1 step ahead.
// ---------------------------------------------------------------------------
__global__ __launch_bounds__(512, 2) void rnn_persist8x(
    const int* __restrict__ tokens, const unsigned char* __restrict__ WhP8,
    const ushort* __restrict__ xwp, float* __restrict__ h_final)
{
    __shared__ char sh[32768];
    char* H0 = sh;            char* H1 = sh + 8192;
    char* TOKB = sh + 16384;

    const int tid  = threadIdx.x;
    const int lane = tid & 63;
    const int wv   = tid >> 6;
    const int r0   = blockIdx.x * 16;

    const int r16  = lane & 15;
    const int q    = lane >> 4;
    const int bswz = r16 << 4;

    for (int f = tid; f < 16 * Tn; f += 512) {
        int row = f >> 9, tt = f & 511;
        *(ushort*)(TOKB + ((((row << 10) | (tt << 1))) ^ (row << 2))) =
            (ushort)tokens[r0 * Tn + f];
    }
    {   // zero H0
        int* z = (int*)sh;
        for (int f = tid; f < 2048; f += 512) z[f] = 0;
    }
    __syncthreads();

    i32x8_t whf[4][4];
#pragma unroll
    for (int kc = 0; kc < 4; ++kc)
#pragma unroll
        for (int p = 0; p < 4; ++p)
            whf[kc][p] = *(const i32x8_t*)(WhP8 +
                (((wv * 4 + p) * 4 + kc) * 64 + lane) * 32);

    // per-thread xw base: thread-identity mapping to xw_gemm's writer
    const ushort* xwT = xwp + ((size_t)blockIdx.x * 512 + tid) * 16;

    float hprev[4][4];
#pragma unroll
    for (int p = 0; p < 4; ++p)
#pragma unroll
        for (int j = 0; j < 4; ++j) hprev[p][j] = 0.f;

    uint4 pfA0, pfA1, pfB0, pfB1;
    pfA0 = *(const uint4*)(xwT);
    pfA1 = *(const uint4*)(xwT + 8);

#define BFL(u) __uint_as_float((u) << 16)
#define BFH(u) __uint_as_float((u) & 0xFFFF0000u)

#define RNN_STEP(T, HC, HN, C0, C1, N0, N1)                                    \
    {                                                                          \
        const int t = (T);                                                     \
        if (t + 1 < Tn) {                                                      \
            const ushort* xt = xwT + (size_t)(t + 1) * XW_STEP;                \
            N0 = *(const uint4*)(xt);                                          \
            N1 = *(const uint4*)(xt + 8);                                      \
        }                                                                      \
        f32x4_t acc[4];                                                        \
        acc[0] = (f32x4_t){BFL(C0.x), BFH(C0.x), BFL(C0.y), BFH(C0.y)};        \
        acc[1] = (f32x4_t){BFL(C0.z), BFH(C0.z), BFL(C0.w), BFH(C0.w)};        \
        acc[2] = (f32x4_t){BFL(C1.x), BFH(C1.x), BFL(C1.y), BFH(C1.y)};        \
        acc[3] = (f32x4_t){BFL(C1.z), BFH(C1.z), BFL(C1.w), BFH(C1.w)};        \
        _Pragma("unroll")                                                      \
        for (int kc = 0; kc < 4; ++kc) {                                       \
            const int bb = r16 * 512 + kc * 128 + q * 32;                      \
            uint4 blo = *(const uint4*)((HC) + ((bb) ^ bswz));                 \
            uint4 bhi = *(const uint4*)((HC) + ((bb + 16) ^ bswz));            \
            i32x8_t bf = {(int)blo.x, (int)blo.y, (int)blo.z, (int)blo.w,      \
                          (int)bhi.x, (int)bhi.y, (int)bhi.z, (int)bhi.w};     \
            _Pragma("unroll")                                                  \
            for (int p = 0; p < 4; ++p)                                        \
                acc[p] = __builtin_amdgcn_mfma_scale_f32_16x16x128_f8f6f4(     \
                    whf[kc][p], bf, acc[p], 0, 0, 0, USC, 0, USC);             \
        }                                                                      \
        const bool mk = *(const ushort*)(TOKB +                                \
            ((((r16 << 10) | (t << 1))) ^ (r16 << 2))) != 0;                   \
        _Pragma("unroll")                                                      \
        for (int p = 0; p < 4; ++p) {                                          \
            float v0 = fmaxf(acc[p][0] * INV, 0.f);                            \
            float v1 = fmaxf(acc[p][1] * INV, 0.f);                            \
            float v2 = fmaxf(acc[p][2] * INV, 0.f);                            \
            float v3 = fmaxf(acc[p][3] * INV, 0.f);                            \
            v0 = mk ? v0 : hprev[p][0];  v1 = mk ? v1 : hprev[p][1];           \
            v2 = mk ? v2 : hprev[p][2];  v3 = mk ? v3 : hprev[p][3];           \
            hprev[p][0] = v0; hprev[p][1] = v1;                                \
            hprev[p][2] = v2; hprev[p][3] = v3;                                \
            *(unsigned*)((HN) +                                                \
                ((r16 * 512 + (wv * 4 + p) * 16 + q * 4) ^ bswz)) =            \
                pk4(v0 * QS, v1 * QS, v2 * QS, v3 * QS);                       \
        }                                                                      \
        __syncthreads();                                                       \
    }

    for (int t2 = 0; t2 < Tn; t2 += 2) {
        RNN_STEP(t2,     H0, H1, pfA0, pfA1, pfB0, pfB1)
        RNN_STEP(t2 + 1, H1, H0, pfB0, pfB1, pfA0, pfA1)
    }
#undef RNN_STEP
#undef BFL
#undef BFH

#pragma unroll
    for (int p = 0; p < 4; ++p) {
        int n = (wv * 4 + p) * 16 + q * 4;
#pragma unroll
        for (int j = 0; j < 4; ++j)
            h_final[(r0 + r16) * Un + n + j] = hprev[p][j];
    }
}

// ---------------------------------------------------------------------------
// Fallback: round-5 persistent kernel (in-loop x@Wx), used when ws is small.
// ---------------------------------------------------------------------------
__global__ __launch_bounds__(512, 2) void rnn_persist8(
    const int* __restrict__ tokens, const float* __restrict__ emb,
    const float* __restrict__ b_rnn,
    const unsigned char* __restrict__ WhP8, const unsigned char* __restrict__ WxP8,
    float* __restrict__ h_final)
{
    __shared__ char sh[36864];
    char* H0 = sh;            char* H1 = sh + 8192;
    char* X0 = sh + 16384;    char* X1 = sh + 18432;
    char* TOKB = sh + 20480;

    const int tid  = threadIdx.x;
    const int lane = tid & 63;
    const int wv   = tid >> 6;
    const int r0   = blockIdx.x * 16;

    const int r16  = lane & 15;
    const int q    = lane >> 4;
    const int bswz = r16 << 4;

    for (int f = tid; f < 16 * Tn; f += 512) {
        int row = f >> 9, tt = f & 511;
        *(ushort*)(TOKB + ((((row << 10) | (tt << 1))) ^ (row << 2))) =
            (ushort)tokens[r0 * Tn + f];
    }
    {
        int* z = (int*)sh;
        for (int f = tid; f < 2048; f += 512) z[f] = 0;
        int* zx = (int*)(sh + 16384);
        for (int f = tid; f < 1024; f += 512) zx[f] = 0;
    }
    __syncthreads();

    i32x8_t whf[4][4], wxf[4];
#pragma unroll
    for (int kc = 0; kc < 4; ++kc)
#pragma unroll
        for (int p = 0; p < 4; ++p)
            whf[kc][p] = *(const i32x8_t*)(WhP8 +
                (((wv * 4 + p) * 4 + kc) * 64 + lane) * 32);
#pragma unroll
    for (int p = 0; p < 4; ++p)
        wxf[p] = *(const i32x8_t*)(WxP8 + ((wv * 4 + p) * 64 + lane) * 32);

    float bias_r[4][4];
#pragma unroll
    for (int p = 0; p < 4; ++p)
#pragma unroll
        for (int j = 0; j < 4; ++j)
            bias_r[p][j] = b_rnn[(wv * 4 + p) * 16 + q * 4 + j];

    const int prow = tid / 25;
    const int pc4  = tid - prow * 25;
    const bool is_pref = (tid < 400);
    const int pxaddr = (prow * 128 + pc4 * 4) ^ (prow << 4);

    if (is_pref) {
        int tk = (int)*(const ushort*)(TOKB + (((prow << 10)) ^ (prow << 2)));
        float4 v = *(const float4*)(emb + tk * En + pc4 * 4);
        *(unsigned*)(X0 + pxaddr) = pk4(v.x * QS, v.y * QS, v.z * QS, v.w * QS);
    }
    __syncthreads();

    float hprev[4][4];
#pragma unroll
    for (int p = 0; p < 4; ++p)
#pragma unroll
        for (int j = 0; j < 4; ++j) hprev[p][j] = 0.f;

#define RNN_STEP(T, HC, HN, XC, XN)                                            \
    {                                                                          \
        const int t = (T);                                                     \
        float4 pref;                                                           \
        const bool dp = is_pref && (t + 1 < Tn);                               \
        if (dp) {                                                              \
            int tk = (int)*(const ushort*)(TOKB +                              \
                ((((prow << 10) | ((t + 1) << 1))) ^ (prow << 2)));            \
            pref = *(const float4*)(emb + tk * En + pc4 * 4);                  \
        }                                                                      \
        f32x4_t acc[4];                                                        \
        _Pragma("unroll")                                                      \
        for (int p = 0; p < 4; ++p) acc[p] = (f32x4_t){0.f, 0.f, 0.f, 0.f};    \
        _Pragma("unroll")                                                      \
        for (int kc = 0; kc < 4; ++kc) {                                       \
            const int bb = r16 * 512 + kc * 128 + q * 32;                      \
            uint4 blo = *(const uint4*)((HC) + ((bb) ^ bswz));                 \
            uint4 bhi = *(const uint4*)((HC) + ((bb + 16) ^ bswz));            \
            i32x8_t bf = {(int)blo.x, (int)blo.y, (int)blo.z, (int)blo.w,      \
                          (int)bhi.x, (int)bhi.y, (int)bhi.z, (int)bhi.w};     \
            _Pragma("unroll")                                                  \
            for (int p = 0; p < 4; ++p)                                        \
                acc[p] = __builtin_amdgcn_mfma_scale_f32_16x16x128_f8f6f4(     \
                    whf[kc][p], bf, acc[p], 0, 0, 0, USC, 0, USC);             \
        }                                                                      \
        {                                                                      \
            const int xb = r16 * 128 + q * 32;                                 \
            uint4 blo = *(const uint4*)((XC) + ((xb) ^ bswz));                 \
            uint4 bhi = *(const uint4*)((XC) + ((xb + 16) ^ bswz));            \
            i32x8_t bf = {(int)blo.x, (int)blo.y, (int)blo.z, (int)blo.w,      \
                          (int)bhi.x, (int)bhi.y, (int)bhi.z, (int)bhi.w};     \
            _Pragma("unroll")                                                  \
            for (int p = 0; p < 4; ++p)                                        \
                acc[p] = __builtin_amdgcn_mfma_scale_f32_16x16x128_f8f6f4(     \
                    wxf[p], bf, acc[p], 0, 0, 0, USC, 0, USC);                 \
        }                                                                      \
        const bool mk = *(const ushort*)(TOKB +                                \
            ((((r16 << 10) | (t << 1))) ^ (r16 << 2))) != 0;                   \
        _Pragma("unroll")                                                      \
        for (int p = 0; p < 4; ++p) {                                          \
            float v0 = fmaxf(acc[p][0] * INV + bias_r[p][0], 0.f);             \
            float v1 = fmaxf(acc[p][1] * INV + bias_r[p][1], 0.f);             \
            float v2 = fmaxf(acc[p][2] * INV + bias_r[p][2], 0.f);             \
            float v3 = fmaxf(acc[p][3] * INV + bias_r[p][3], 0.f);             \
            v0 = mk ? v0 : hprev[p][0];  v1 = mk ? v1 : hprev[p][1];           \
            v2 = mk ? v2 : hprev[p][2];  v3 = mk ? v3 : hprev[p][3];           \
            hprev[p][0] = v0; hprev[p][1] = v1;                                \
            hprev[p][2] = v2; hprev[p][3] = v3;                                \
            *(unsigned*)((HN) +                                                \
                ((r16 * 512 + (wv * 4 + p) * 16 + q * 4) ^ bswz)) =            \
                pk4(v0 * QS, v1 * QS, v2 * QS, v3 * QS);                       \
        }                                                                      \
        if (dp) {                                                              \
            *(unsigned*)((XN) + pxaddr) =                                      \
                pk4(pref.x * QS, pref.y * QS, pref.z * QS, pref.w * QS);       \
        }                                                                      \
        __syncthreads();                                                       \
    }

    for (int t2 = 0; t2 < Tn; t2 += 2) {
        RNN_STEP(t2,     H0, H1, X0, X1)
        RNN_STEP(t2 + 1, H1, H0, X1, X0)
    }
#undef RNN_STEP

#pragma unroll
    for (int p = 0; p < 4; ++p) {
        int n = (wv * 4 + p) * 16 + q * 4;
#pragma unroll
        for (int j = 0; j < 4; ++j)
            h_final[(r0 + r16) * Un + n + j] = hprev[p][j];
    }
}

// ---------------------------------------------------------------------------
// MLP: 32-row tiles, K staged in 512-chunks (64 KB LDS).
// ---------------------------------------------------------------------------
template <int K, bool RELU>
__global__ __launch_bounds__(256) void fc32(
    const float* __restrict__ in, const float* __restrict__ W,
    const float* __restrict__ b, float* __restrict__ out, int N)
{
    __shared__ float in_lds[32][512];
    const int tid = threadIdx.x;
    const int r0  = blockIdx.y * 32;
    const int c0  = blockIdx.x * 32;

    const int col = c0 + (tid & 31);
    const int rq  = (tid >> 5) * 4;     // 4 rows per thread

    float acc0 = b[col], acc1 = acc0, acc2 = acc0, acc3 = acc0;

    for (int kc = 0; kc < K / 512; ++kc) {
        if (kc) __syncthreads();
        for (int i = tid; i < 32 * 512; i += 256) {
            int r = i >> 9, c = i & 511;
            in_lds[r][c] = in[(r0 + r) * K + kc * 512 + c];
        }
        __syncthreads();

        const float4* v0 = (const float4*)(&in_lds[rq + 0][0]);
        const float4* v1 = (const float4*)(&in_lds[rq + 1][0]);
        const float4* v2 = (const float4*)(&in_lds[rq + 2][0]);
        const float4* v3 = (const float4*)(&in_lds[rq + 3][0]);
        for (int k4 = 0; k4 < 128; ++k4) {
            float4 a0 = v0[k4], a1 = v1[k4], a2 = v2[k4], a3 = v3[k4];
            int k = kc * 512 + k4 * 4;
            float w0 = W[(k + 0) * N + col];
            float w1 = W[(k + 1) * N + col];
            float w2 = W[(k + 2) * N + col];
            float w3 = W[(k + 3) * N + col];
            acc0 += a0.x * w0 + a0.y * w1 + a0.z * w2 + a0.w * w3;
            acc1 += a1.x * w0 + a1.y * w1 + a1.z * w2 + a1.w * w3;
            acc2 += a2.x * w0 + a2.y * w1 + a2.z * w2 + a2.w * w3;
            acc3 += a3.x * w0 + a3.y * w1 + a3.z * w2 + a3.w * w3;
        }
    }
    if (RELU) {
        acc0 = fmaxf(acc0, 0.f); acc1 = fmaxf(acc1, 0.f);
        acc2 = fmaxf(acc2, 0.f); acc3 = fmaxf(acc3, 0.f);
    }
    out[(r0 + rq + 0) * N + col] = acc0;
    out[(r0 + rq + 1) * N + col] = acc1;
    out[(r0 + rq + 2) * N + col] = acc2;
    out[(r0 + rq + 3) * N + col] = acc3;
}

__global__ __launch_bounds__(64) void head_softmax(
    const float* __restrict__ h2, const float* __restrict__ Wo,
    const float* __restrict__ bo, float* __restrict__ out)
{
    const int b    = blockIdx.x;
    const int lane = threadIdx.x;

    float acc[Cn];
#pragma unroll
    for (int c = 0; c < Cn; ++c) acc[c] = 0.f;

    for (int k = lane; k < D2n; k += 64) {
        float hv = h2[b * D2n + k];
#pragma unroll
        for (int c = 0; c < Cn; ++c) acc[c] += hv * Wo[k * Cn + c];
    }
#pragma unroll
    for (int c = 0; c < Cn; ++c) {
#pragma unroll
        for (int off = 32; off > 0; off >>= 1)
            acc[c] += __shfl_down(acc[c], off);
    }
    if (lane == 0) {
        float l[Cn], mx = -1e30f;
#pragma unroll
        for (int c = 0; c < Cn; ++c) { l[c] = acc[c] + bo[c]; mx = fmaxf(mx, l[c]); }
        float s = 0.f;
#pragma unroll
        for (int c = 0; c < Cn; ++c) { l[c] = __expf(l[c] - mx); s += l[c]; }
        float inv = 1.f / s;
#pragma unroll
        for (int c = 0; c < Cn; ++c) out[b * Cn + c] = l[c] * inv;
    }
}

extern "C" void kernel_launch(void* const* d_in, const int* in_sizes, int n_in,
                              void* d_out, int out_size, void* d_ws, size_t ws_size,
                              hipStream_t stream)
{
    const int*   tokens = (const int*)d_in[0];
    const float* emb    = (const float*)d_in[1];
    const float* Wx     = (const float*)d_in[2];
    const float* Wh     = (const float*)d_in[3];
    const float* b_rnn  = (const float*)d_in[4];
    const float* W1     = (const float*)d_in[5];
    const float* b1     = (const float*)d_in[6];
    const float* W2     = (const float*)d_in[7];
    const float* b2     = (const float*)d_in[8];
    const float* Wo     = (const float*)d_in[9];
    const float* bo     = (const float*)d_in[10];
    float* out = (float*)d_out;

    char* ws = (char*)d_ws;
    unsigned char* WhP8 = (unsigned char*)ws;                 // 256 KB
    unsigned char* WxP8 = (unsigned char*)(ws + (256 << 10)); // 64 KB
    float* h_last = (float*)(ws + (320 << 10));               // 512 KB
    float* h1     = (float*)(ws + (832 << 10));               // 1 MB
    float* h2     = (float*)(ws + (1856 << 10));              // 1 MB
    ushort* xwp   = (ushort*)(ws + (3u << 20));               // 128 MB
    const size_t need = (3u << 20) + (size_t)Tn * 16 * 512 * 16 * sizeof(ushort);

    pack_wh8<<<1024, 256, 0, stream>>>(Wh, WhP8);
    pack_wx8<<<256, 256, 0, stream>>>(Wx, WxP8);

    if (ws_size >= need) {
        xw_gemm<<<dim3(16, 32), 512, 0, stream>>>(tokens, emb, b_rnn, WxP8, xwp);
        rnn_persist8x<<<Bn / 16, 512, 0, stream>>>(tokens, WhP8, xwp, h_last);
    } else {
        rnn_persist8<<<Bn / 16, 512, 0, stream>>>(
            tokens, emb, b_rnn, WhP8, WxP8, h_last);
    }

    dim3 bs(256);
    fc32<Un, true><<<dim3(D1n / 32, Bn / 32), bs, 0, stream>>>(h_last, W1, b1, h1, D1n);
    fc32<D1n, true><<<dim3(D2n / 32, Bn / 32), bs, 0, stream>>>(h1, W2, b2, h2, D2n);
    head_softmax<<<Bn, 64, 0, stream>>>(h2, Wo, bo, out);
}

// Round 9
// 551.885 us; speedup vs baseline: 1.5847x; 1.1078x over previous
//
#include <hip/hip_runtime.h>

// Round 9: round-8 structure with the xw scaling bug fixed.
// Root cause of r8 failure: xwp stored QS^2-scaled values (correct as MFMA
// C-init in r7) but the new epilogue FMA adds xw WITHOUT the INV descale ->
// 65536x too large. Fix: xw_gemm now stores the TRUE value bf16(acc*INV).
// Keeps: relaxed barrier (lgkmcnt(0)+s_barrier, vmcnt in flight - T4),
// epilogue-FMA xw fold, token-mask bitmap, unconditional padded prefetch.

typedef __attribute__((ext_vector_type(8))) int i32x8_t;
typedef __attribute__((ext_vector_type(4))) float f32x4_t;

constexpr int Bn = 256, Tn = 512, En = 100, Un = 512;
constexpr int D1n = 1024, D2n = 1024, Cn = 10;
constexpr float QS  = 256.f;               // quant scale 2^8
constexpr float INV = 1.52587890625e-05f;  // 2^-16
constexpr int USC = 0x7F7F7F7F;            // unit E8M0 scales (2^0)
constexpr int XW_STEP = 16 * 512 * 16;     // ushorts per t-slice (256 KB)

// ---- fp8 e4m3fn conversion helpers ----------------------------------------
__device__ __forceinline__ unsigned f2e4m3_sw(float x) {
    unsigned u = __float_as_uint(x);
    unsigned sgn = (u >> 24) & 0x80;
    float a = __uint_as_float(u & 0x7FFFFFFF);
    if (a >= 448.f) return sgn | 0x7E;
    if (a < 0.015625f) {
        unsigned q = (unsigned)__float2int_rn(a * 512.f);
        return sgn | q;
    }
    int e = (int)((u >> 23) & 0xFF) - 127;
    unsigned m = u & 0x7FFFFF;
    unsigned mant = m >> 20, rem = m & 0xFFFFF;
    if (rem > 0x80000 || (rem == 0x80000 && (mant & 1))) {
        if (++mant == 8) { mant = 0; ++e; }
    }
    if (e > 8) return sgn | 0x7E;
    return sgn | ((unsigned)(e + 7) << 3) | mant;
}

__device__ __forceinline__ unsigned cvt1(float x) {
#if __has_builtin(__builtin_amdgcn_cvt_pk_fp8_f32)
    return (unsigned)__builtin_amdgcn_cvt_pk_fp8_f32(x, x, 0, false) & 0xFFu;
#else
    return f2e4m3_sw(x);
#endif
}

__device__ __forceinline__ unsigned pk4(float a, float b, float c, float d) {
#if __has_builtin(__builtin_amdgcn_cvt_pk_fp8_f32)
    int r = __builtin_amdgcn_cvt_pk_fp8_f32(a, b, 0, false);
    r = __builtin_amdgcn_cvt_pk_fp8_f32(c, d, r, true);
    return (unsigned)r;
#else
    return f2e4m3_sw(a) | (f2e4m3_sw(b) << 8) | (f2e4m3_sw(c) << 16) |
           (f2e4m3_sw(d) << 24);
#endif
}

__device__ __forceinline__ ushort f2bf(float x) {
    unsigned u = __float_as_uint(x);
    unsigned r = (u + 0x7FFFu + ((u >> 16) & 1u)) >> 16;   // RNE
    return (ushort)r;
}

// relaxed barrier: LDS visibility only; vmcnt survives (T4)
__device__ __forceinline__ void lds_barrier() {
    asm volatile("s_waitcnt lgkmcnt(0)" ::: "memory");
    __builtin_amdgcn_s_barrier();
}

// ---------------------------------------------------------------------------
// Pack Wh [512][512] f32 -> fp8 MX A-fragment order (scaled by QS).
// ---------------------------------------------------------------------------
__global__ __launch_bounds__(256) void pack_wh8(const float* __restrict__ Wh,
                                                unsigned char* __restrict__ P) {
    int e = blockIdx.x * 256 + threadIdx.x;          // < 262144
    int j = e & 31, l = (e >> 5) & 63, kc = (e >> 11) & 3, nt = e >> 13;
    int k = kc * 128 + (l >> 4) * 32 + j;
    int c = nt * 16 + (l & 15);
    P[e] = (unsigned char)cvt1(Wh[k * Un + c] * QS);
}

__global__ __launch_bounds__(256) void pack_wx8(const float* __restrict__ Wx,
                                                unsigned char* __restrict__ P) {
    int e = blockIdx.x * 256 + threadIdx.x;          // < 65536
    int j = e & 31, l = (e >> 5) & 63, nt = e >> 11;
    int k = (l >> 4) * 32 + j;
    int c = nt * 16 + (l & 15);
    P[e] = (k < En) ? (unsigned char)cvt1(Wx[k * Un + c] * QS) : 0;
}

// ---------------------------------------------------------------------------
// xw_gemm: xwp = bf16( (x_fp8 @ Wx_fp8)*INV + b_rnn )  -- TRUE (descaled)
// value, per-thread-contiguous xwp[((t*16+blk)*512 + tid)*16 .. +16).
// ---------------------------------------------------------------------------
__global__ __launch_bounds__(512) void xw_gemm(
    const int* __restrict__ tokens, const float* __restrict__ emb,
    const float* __restrict__ b_rnn, const unsigned char* __restrict__ WxP8,
    ushort* __restrict__ xwp)
{
    __shared__ char XS[32768];       // 16 slabs of [16 rows][128 k] fp8

    const int tid  = threadIdx.x;
    const int lane = tid & 63;
    const int wv   = tid >> 6;
    const int r0   = blockIdx.x * 16;
    const int t0   = blockIdx.y * 16;

    const int r16 = lane & 15;
    const int q   = lane >> 4;

    for (int idx = tid; idx < 6400; idx += 512) {
        int tt   = idx / 400;
        int rem  = idx - tt * 400;
        int prow = rem / 25;
        int pc4  = rem - prow * 25;
        int tok  = tokens[(r0 + prow) * Tn + t0 + tt];
        float4 v = *(const float4*)(emb + tok * En + pc4 * 4);
        *(unsigned*)(XS + tt * 2048 + ((prow * 128 + pc4 * 4) ^ (prow << 4))) =
            pk4(v.x * QS, v.y * QS, v.z * QS, v.w * QS);
    }
    for (int idx = tid; idx < 16 * 16 * 7; idx += 512) {
        int tt   = idx / 112;
        int rem  = idx - tt * 112;
        int prow = rem / 7;
        int c4   = 25 + (rem - prow * 7);
        *(unsigned*)(XS + tt * 2048 + ((prow * 128 + c4 * 4) ^ (prow << 4))) = 0;
    }
    __syncthreads();

    i32x8_t wxf[4];
#pragma unroll
    for (int p = 0; p < 4; ++p)
        wxf[p] = *(const i32x8_t*)(WxP8 + ((wv * 4 + p) * 64 + lane) * 32);

    float bias_r[4][4];
#pragma unroll
    for (int p = 0; p < 4; ++p)
#pragma unroll
        for (int j = 0; j < 4; ++j)
            bias_r[p][j] = b_rnn[(wv * 4 + p) * 16 + q * 4 + j];

    const int bswz = r16 << 4;
    for (int tt = 0; tt < 16; ++tt) {
        uint4 blo = *(const uint4*)(XS + tt * 2048 +
                        ((r16 * 128 + q * 32) ^ bswz));
        uint4 bhi = *(const uint4*)(XS + tt * 2048 +
                        (((r16 * 128 + q * 32) + 16) ^ bswz));
        i32x8_t bf = {(int)blo.x, (int)blo.y, (int)blo.z, (int)blo.w,
                      (int)bhi.x, (int)bhi.y, (int)bhi.z, (int)bhi.w};
        f32x4_t acc[4];
#pragma unroll
        for (int p = 0; p < 4; ++p) {
            acc[p] = (f32x4_t){0.f, 0.f, 0.f, 0.f};
            acc[p] = __builtin_amdgcn_mfma_scale_f32_16x16x128_f8f6f4(
                wxf[p], bf, acc[p], 0, 0, 0, USC, 0, USC);
        }
        // descale to TRUE values, add bias, store bf16
        float v[4][4];
#pragma unroll
        for (int p = 0; p < 4; ++p)
#pragma unroll
            for (int j = 0; j < 4; ++j)
                v[p][j] = fmaf(acc[p][j], INV, bias_r[p][j]);

        size_t base = (((size_t)(t0 + tt) * 16 + blockIdx.x) * 512 + tid) * 16;
        uint4 lo, hi;
        lo.x = (unsigned)f2bf(v[0][0]) | ((unsigned)f2bf(v[0][1]) << 16);
        lo.y = (unsigned)f2bf(v[0][2]) | ((unsigned)f2bf(v[0][3]) << 16);
        lo.z = (unsigned)f2bf(v[1][0]) | ((unsigned)f2bf(v[1][1]) << 16);
        lo.w = (unsigned)f2bf(v[1][2]) | ((unsigned)f2bf(v[1][3]) << 16);
        hi.x = (unsigned)f2bf(v[2][0]) | ((unsigned)f2bf(v[2][1]) << 16);
        hi.y = (unsigned)f2bf(v[2][2]) | ((unsigned)f2bf(v[2][3]) << 16);
        hi.z = (unsigned)f2bf(v[3][0]) | ((unsigned)f2bf(v[3][1]) << 16);
        hi.w = (unsigned)f2bf(v[3][2]) | ((unsigned)f2bf(v[3][3]) << 16);
        *(uint4*)(xwp + base)     = lo;
        *(uint4*)(xwp + base + 8) = hi;
    }
}

// ---------------------------------------------------------------------------
// Slim persistent RNN. LDS: H0@0(8192) H1@8192 TOKM@16384(1KB) = 17.5 KB.
// ---------------------------------------------------------------------------
__global__ __launch_bounds__(512, 2) void rnn_persist8x(
    const int* __restrict__ tokens, const unsigned char* __restrict__ WhP8,
    const ushort* __restrict__ xwp, float* __restrict__ h_final)
{
    __shared__ char sh[17408];
    char* H0 = sh;            char* H1 = sh + 8192;
    unsigned* TOKM = (unsigned*)(sh + 16384);

    const int tid  = threadIdx.x;
    const int lane = tid & 63;
    const int wv   = tid >> 6;
    const int r0   = blockIdx.x * 16;

    const int r16  = lane & 15;
    const int q    = lane >> 4;
    const int bswz = r16 << 4;

    // token mask bitmap: row r, chunk c -> bit i = (tokens[r][c*32+i] != 0)
    if (tid < 256) {
        int row = tid >> 4, ch = tid & 15;
        const int* tp = tokens + (r0 + row) * Tn + ch * 32;
        unsigned m = 0;
#pragma unroll
        for (int i = 0; i < 32; ++i) m |= (tp[i] != 0 ? 1u : 0u) << i;
        TOKM[row * 16 + ch] = m;
    }
    {   // zero H0
        int* z = (int*)sh;
        for (int f = tid; f < 2048; f += 512) z[f] = 0;
    }
    __syncthreads();

    i32x8_t whf[4][4];
#pragma unroll
    for (int kc = 0; kc < 4; ++kc)
#pragma unroll
        for (int p = 0; p < 4; ++p)
            whf[kc][p] = *(const i32x8_t*)(WhP8 +
                (((wv * 4 + p) * 4 + kc) * 64 + lane) * 32);

    const ushort* xwT = xwp + ((size_t)blockIdx.x * 512 + tid) * 16;
    const ushort* xnext = xwT + XW_STEP;

    float hprev[4][4];
#pragma unroll
    for (int p = 0; p < 4; ++p)
#pragma unroll
        for (int j = 0; j < 4; ++j) hprev[p][j] = 0.f;

    uint4 pfA0 = *(const uint4*)(xwT);
    uint4 pfA1 = *(const uint4*)(xwT + 8);
    uint4 pfB0, pfB1;

#define BFL(u) __uint_as_float((u) << 16)
#define BFH(u) __uint_as_float((u) & 0xFFFF0000u)

#define RNN_STEP(HC, HN, C0, C1, N0, N1, MK)                                   \
    {                                                                          \
        N0 = *(const uint4*)(xnext);                                           \
        N1 = *(const uint4*)(xnext + 8);                                       \
        xnext += XW_STEP;                                                      \
        f32x4_t acc[4];                                                        \
        _Pragma("unroll")                                                      \
        for (int p = 0; p < 4; ++p) acc[p] = (f32x4_t){0.f, 0.f, 0.f, 0.f};    \
        _Pragma("unroll")                                                      \
        for (int kc = 0; kc < 4; ++kc) {                                       \
            const int bb = r16 * 512 + kc * 128 + q * 32;                      \
            uint4 blo = *(const uint4*)((HC) + ((bb) ^ bswz));                 \
            uint4 bhi = *(const uint4*)((HC) + ((bb + 16) ^ bswz));            \
            i32x8_t bf = {(int)blo.x, (int)blo.y, (int)blo.z, (int)blo.w,      \
                          (int)bhi.x, (int)bhi.y, (int)bhi.z, (int)bhi.w};     \
            _Pragma("unroll")                                                  \
            for (int p = 0; p < 4; ++p)                                        \
                acc[p] = __builtin_amdgcn_mfma_scale_f32_16x16x128_f8f6f4(     \
                    whf[kc][p], bf, acc[p], 0, 0, 0, USC, 0, USC);             \
        }                                                                      \
        const bool mk = (MK);                                                  \
        _Pragma("unroll")                                                      \
        for (int p = 0; p < 4; ++p) {                                          \
            unsigned wlo = (p < 2) ? ((p & 1) ? C0.z : C0.x)                   \
                                   : ((p & 1) ? C1.z : C1.x);                  \
            unsigned whi = (p < 2) ? ((p & 1) ? C0.w : C0.y)                   \
                                   : ((p & 1) ? C1.w : C1.y);                  \
            float v0 = fmaxf(fmaf(acc[p][0], INV, BFL(wlo)), 0.f);             \
            float v1 = fmaxf(fmaf(acc[p][1], INV, BFH(wlo)), 0.f);             \
            float v2 = fmaxf(fmaf(acc[p][2], INV, BFL(whi)), 0.f);             \
            float v3 = fmaxf(fmaf(acc[p][3], INV, BFH(whi)), 0.f);             \
            v0 = mk ? v0 : hprev[p][0];  v1 = mk ? v1 : hprev[p][1];           \
            v2 = mk ? v2 : hprev[p][2];  v3 = mk ? v3 : hprev[p][3];           \
            hprev[p][0] = v0; hprev[p][1] = v1;                                \
            hprev[p][2] = v2; hprev[p][3] = v3;                                \
            *(unsigned*)((HN) +                                                \
                ((r16 * 512 + (wv * 4 + p) * 16 + q * 4) ^ bswz)) =            \
                pk4(v0 * QS, v1 * QS, v2 * QS, v3 * QS);                       \
        }                                                                      \
        lds_barrier();                                                         \
    }

    const unsigned* mrow = TOKM + r16 * 16;
    for (int tc = 0; tc < 16; ++tc) {
        unsigned m32 = mrow[tc];
        for (int ii = 0; ii < 16; ++ii) {
            RNN_STEP(H0, H1, pfA0, pfA1, pfB0, pfB1, (m32 & 1u) != 0) m32 >>= 1;
            RNN_STEP(H1, H0, pfB0, pfB1, pfA0, pfA1, (m32 & 1u) != 0) m32 >>= 1;
        }
    }
#undef RNN_STEP
#undef BFL
#undef BFH

#pragma unroll
    for (int p = 0; p < 4; ++p) {
        int n = (wv * 4 + p) * 16 + q * 4;
#pragma unroll
        for (int j = 0; j < 4; ++j)
            h_final[(r0 + r16) * Un + n + j] = hprev[p][j];
    }
}

// ---------------------------------------------------------------------------
// Fallback: round-5 persistent kernel (in-loop x@Wx), used when ws is small.
// ---------------------------------------------------------------------------
__global__ __launch_bounds__(512, 2) void rnn_persist8(
    const int* __restrict__ tokens, const float* __restrict__ emb,
    const float* __restrict__ b_rnn,
    const unsigned char* __restrict__ WhP8, const unsigned char* __restrict__ WxP8,
    float* __restrict__ h_final)
{
    __shared__ char sh[36864];
    char* H0 = sh;            char* H1 = sh + 8192;
    char* X0 = sh + 16384;    char* X1 = sh + 18432;
    char* TOKB = sh + 20480;

    const int tid  = threadIdx.x;
    const int lane = tid & 63;
    const int wv   = tid >> 6;
    const int r0   = blockIdx.x * 16;

    const int r16  = lane & 15;
    const int q    = lane >> 4;
    const int bswz = r16 << 4;

    for (int f = tid; f < 16 * Tn; f += 512) {
        int row = f >> 9, tt = f & 511;
        *(ushort*)(TOKB + ((((row << 10) | (tt << 1))) ^ (row << 2))) =
            (ushort)tokens[r0 * Tn + f];
    }
    {
        int* z = (int*)sh;
        for (int f = tid; f < 2048; f += 512) z[f] = 0;
        int* zx = (int*)(sh + 16384);
        for (int f = tid; f < 1024; f += 512) zx[f] = 0;
    }
    __syncthreads();

    i32x8_t whf[4][4], wxf[4];
#pragma unroll
    for (int kc = 0; kc < 4; ++kc)
#pragma unroll
        for (int p = 0; p < 4; ++p)
            whf[kc][p] = *(const i32x8_t*)(WhP8 +
                (((wv * 4 + p) * 4 + kc) * 64 + lane) * 32);
#pragma unroll
    for (int p = 0; p < 4; ++p)
        wxf[p] = *(const i32x8_t*)(WxP8 + ((wv * 4 + p) * 64 + lane) * 32);

    float bias_r[4][4];
#pragma unroll
    for (int p = 0; p < 4; ++p)
#pragma unroll
        for (int j = 0; j < 4; ++j)
            bias_r[p][j] = b_rnn[(wv * 4 + p) * 16 + q * 4 + j];

    const int prow = tid / 25;
    const int pc4  = tid - prow * 25;
    const bool is_pref = (tid < 400);
    const int pxaddr = (prow * 128 + pc4 * 4) ^ (prow << 4);

    if (is_pref) {
        int tk = (int)*(const ushort*)(TOKB + (((prow << 10)) ^ (prow << 2)));
        float4 v = *(const float4*)(emb + tk * En + pc4 * 4);
        *(unsigned*)(X0 + pxaddr) = pk4(v.x * QS, v.y * QS, v.z * QS, v.w * QS);
    }
    __syncthreads();

    float hprev[4][4];
#pragma unroll
    for (int p = 0; p < 4; ++p)
#pragma unroll
        for (int j = 0; j < 4; ++j) hprev[p][j] = 0.f;

#define RNN_STEP(T, HC, HN, XC, XN)                                            \
    {                                                                          \
        const int t = (T);                                                     \
        float4 pref;                                                           \
        const bool dp = is_pref && (t + 1 < Tn);                               \
        if (dp) {                                                              \
            int tk = (int)*(const ushort*)(TOKB +                              \
                ((((prow << 10) | ((t + 1) << 1))) ^ (prow << 2)));            \
            pref = *(const float4*)(emb + tk * En + pc4 * 4);                  \
        }                                                                      \
        f32x4_t acc[4];                                                        \
        _Pragma("unroll")                                                      \
        for (int p = 0; p < 4; ++p) acc[p] = (f32x4_t){0.f, 0.f, 0.f, 0.f};    \
        _Pragma("unroll")                                                      \
        for (int kc = 0; kc < 4; ++kc) {                                       \
            const int bb = r16 * 512 + kc * 128 + q * 32;                      \
            uint4 blo = *(const uint4*)((HC) + ((bb) ^ bswz));                 \
            uint4 bhi = *(const uint4*)((HC) + ((bb + 16) ^ bswz));            \
            i32x8_t bf = {(int)blo.x, (int)blo.y, (int)blo.z, (int)blo.w,      \
                          (int)bhi.x, (int)bhi.y, (int)bhi.z, (int)bhi.w};     \
            _Pragma("unroll")                                                  \
            for (int p = 0; p < 4; ++p)                                        \
                acc[p] = __builtin_amdgcn_mfma_scale_f32_16x16x128_f8f6f4(     \
                    whf[kc][p], bf, acc[p], 0, 0, 0, USC, 0, USC);             \
        }                                                                      \
        {                                                                      \
            const int xb = r16 * 128 + q * 32;                                 \
            uint4 blo = *(const uint4*)((XC) + ((xb) ^ bswz));                 \
            uint4 bhi = *(const uint4*)((XC) + ((xb + 16) ^ bswz));            \
            i32x8_t bf = {(int)blo.x, (int)blo.y, (int)blo.z, (int)blo.w,      \
                          (int)bhi.x, (int)bhi.y, (int)bhi.z, (int)bhi.w};     \
            _Pragma("unroll")                                                  \
            for (int p = 0; p < 4; ++p)                                        \
                acc[p] = __builtin_amdgcn_mfma_scale_f32_16x16x128_f8f6f4(     \
                    wxf[p], bf, acc[p], 0, 0, 0, USC, 0, USC);                 \
        }                                                                      \
        const bool mk = *(const ushort*)(TOKB +                                \
            ((((r16 << 10) | (t << 1))) ^ (r16 << 2))) != 0;                   \
        _Pragma("unroll")                                                      \
        for (int p = 0; p < 4; ++p) {                                          \
            float v0 = fmaxf(acc[p][0] * INV + bias_r[p][0], 0.f);             \
            float v1 = fmaxf(acc[p][1] * INV + bias_r[p][1], 0.f);             \
            float v2 = fmaxf(acc[p][2] * INV + bias_r[p][2], 0.f);             \
            float v3 = fmaxf(acc[p][3] * INV + bias_r[p][3], 0.f);             \
            v0 = mk ? v0 : hprev[p][0];  v1 = mk ? v1 : hprev[p][1];           \
            v2 = mk ? v2 : hprev[p][2];  v3 = mk ? v3 : hprev[p][3];           \
            hprev[p][0] = v0; hprev[p][1] = v1;                                \
            hprev[p][2] = v2; hprev[p][3] = v3;                                \
            *(unsigned*)((HN) +                                                \
                ((r16 * 512 + (wv * 4 + p) * 16 + q * 4) ^ bswz)) =            \
                pk4(v0 * QS, v1 * QS, v2 * QS, v3 * QS);                       \
        }                                                                      \
        if (dp) {                                                              \
            *(unsigned*)((XN) + pxaddr) =                                      \
                pk4(pref.x * QS, pref.y * QS, pref.z * QS, pref.w * QS);       \
        }                                                                      \
        __syncthreads();                                                       \
    }

    for (int t2 = 0; t2 < Tn; t2 += 2) {
        RNN_STEP(t2,     H0, H1, X0, X1)
        RNN_STEP(t2 + 1, H1, H0, X1, X0)
    }
#undef RNN_STEP

#pragma unroll
    for (int p = 0; p < 4; ++p) {
        int n = (wv * 4 + p) * 16 + q * 4;
#pragma unroll
        for (int j = 0; j < 4; ++j)
            h_final[(r0 + r16) * Un + n + j] = hprev[p][j];
    }
}

// ---------------------------------------------------------------------------
// MLP: 32-row tiles, K staged in 512-chunks (64 KB LDS).
// ---------------------------------------------------------------------------
template <int K, bool RELU>
__global__ __launch_bounds__(256) void fc32(
    const float* __restrict__ in, const float* __restrict__ W,
    const float* __restrict__ b, float* __restrict__ out, int N)
{
    __shared__ float in_lds[32][512];
    const int tid = threadIdx.x;
    const int r0  = blockIdx.y * 32;
    const int c0  = blockIdx.x * 32;

    const int col = c0 + (tid & 31);
    const int rq  = (tid >> 5) * 4;     // 4 rows per thread

    float acc0 = b[col], acc1 = acc0, acc2 = acc0, acc3 = acc0;

    for (int kc = 0; kc < K / 512; ++kc) {
        if (kc) __syncthreads();
        for (int i = tid; i < 32 * 512; i += 256) {
            int r = i >> 9, c = i & 511;
            in_lds[r][c] = in[(r0 + r) * K + kc * 512 + c];
        }
        __syncthreads();

        const float4* v0 = (const float4*)(&in_lds[rq + 0][0]);
        const float4* v1 = (const float4*)(&in_lds[rq + 1][0]);
        const float4* v2 = (const float4*)(&in_lds[rq + 2][0]);
        const float4* v3 = (const float4*)(&in_lds[rq + 3][0]);
        for (int k4 = 0; k4 < 128; ++k4) {
            float4 a0 = v0[k4], a1 = v1[k4], a2 = v2[k4], a3 = v3[k4];
            int k = kc * 512 + k4 * 4;
            float w0 = W[(k + 0) * N + col];
            float w1 = W[(k + 1) * N + col];
            float w2 = W[(k + 2) * N + col];
            float w3 = W[(k + 3) * N + col];
            acc0 += a0.x * w0 + a0.y * w1 + a0.z * w2 + a0.w * w3;
            acc1 += a1.x * w0 + a1.y * w1 + a1.z * w2 + a1.w * w3;
            acc2 += a2.x * w0 + a2.y * w1 + a2.z * w2 + a2.w * w3;
            acc3 += a3.x * w0 + a3.y * w1 + a3.z * w2 + a3.w * w3;
        }
    }
    if (RELU) {
        acc0 = fmaxf(acc0, 0.f); acc1 = fmaxf(acc1, 0.f);
        acc2 = fmaxf(acc2, 0.f); acc3 = fmaxf(acc3, 0.f);
    }
    out[(r0 + rq + 0) * N + col] = acc0;
    out[(r0 + rq + 1) * N + col] = acc1;
    out[(r0 + rq + 2) * N + col] = acc2;
    out[(r0 + rq + 3) * N + col] = acc3;
}

__global__ __launch_bounds__(64) void head_softmax(
    const float* __restrict__ h2, const float* __restrict__ Wo,
    const float* __restrict__ bo, float* __restrict__ out)
{
    const int b    = blockIdx.x;
    const int lane = threadIdx.x;

    float acc[Cn];
#pragma unroll
    for (int c = 0; c < Cn; ++c) acc[c] = 0.f;

    for (int k = lane; k < D2n; k += 64) {
        float hv = h2[b * D2n + k];
#pragma unroll
        for (int c = 0; c < Cn; ++c) acc[c] += hv * Wo[k * Cn + c];
    }
#pragma unroll
    for (int c = 0; c < Cn; ++c) {
#pragma unroll
        for (int off = 32; off > 0; off >>= 1)
            acc[c] += __shfl_down(acc[c], off);
    }
    if (lane == 0) {
        float l[Cn], mx = -1e30f;
#pragma unroll
        for (int c = 0; c < Cn; ++c) { l[c] = acc[c] + bo[c]; mx = fmaxf(mx, l[c]); }
        float s = 0.f;
#pragma unroll
        for (int c = 0; c < Cn; ++c) { l[c] = __expf(l[c] - mx); s += l[c]; }
        float inv = 1.f / s;
#pragma unroll
        for (int c = 0; c < Cn; ++c) out[b * Cn + c] = l[c] * inv;
    }
}

extern "C" void kernel_launch(void* const* d_in, const int* in_sizes, int n_in,
                              void* d_out, int out_size, void* d_ws, size_t ws_size,
                              hipStream_t stream)
{
    const int*   tokens = (const int*)d_in[0];
    const float* emb    = (const float*)d_in[1];
    const float* Wx     = (const float*)d_in[2];
    const float* Wh     = (const float*)d_in[3];
    const float* b_rnn  = (const float*)d_in[4];
    const float* W1     = (const float*)d_in[5];
    const float* b1     = (const float*)d_in[6];
    const float* W2     = (const float*)d_in[7];
    const float* b2     = (const float*)d_in[8];
    const float* Wo     = (const float*)d_in[9];
    const float* bo     = (const float*)d_in[10];
    float* out = (float*)d_out;

    char* ws = (char*)d_ws;
    unsigned char* WhP8 = (unsigned char*)ws;                 // 256 KB
    unsigned char* WxP8 = (unsigned char*)(ws + (256 << 10)); // 64 KB
    float* h_last = (float*)(ws + (320 << 10));               // 512 KB
    float* h1     = (float*)(ws + (832 << 10));               // 1 MB
    float* h2     = (float*)(ws + (1856 << 10));              // 1 MB
    ushort* xwp   = (ushort*)(ws + (3u << 20));               // 128.25 MB
    // +1 padded t-slice so the last step's prefetch is in-bounds (unused)
    const size_t need = (3u << 20) +
        (size_t)(Tn + 1) * XW_STEP * sizeof(ushort);

    pack_wh8<<<1024, 256, 0, stream>>>(Wh, WhP8);
    pack_wx8<<<256, 256, 0, stream>>>(Wx, WxP8);

    if (ws_size >= need) {
        xw_gemm<<<dim3(16, 32), 512, 0, stream>>>(tokens, emb, b_rnn, WxP8, xwp);
        rnn_persist8x<<<Bn / 16, 512, 0, stream>>>(tokens, WhP8, xwp, h_last);
    } else {
        rnn_persist8<<<Bn / 16, 512, 0, stream>>>(
            tokens, emb, b_rnn, WhP8, WxP8, h_last);
    }

    dim3 bs(256);
    fc32<Un, true><<<dim3(D1n / 32, Bn / 32), bs, 0, stream>>>(h_last, W1, b1, h1, D1n);
    fc32<D1n, true><<<dim3(D2n / 32, Bn / 32), bs, 0, stream>>>(h1, W2, b2, h2, D2n);
    head_softmax<<<Bn, 64, 0, stream>>>(h2, Wo, bo, out);
}

// Round 10
// 546.038 us; speedup vs baseline: 1.6016x; 1.0107x over previous
//
#include <hip/hip_runtime.h>

// Round 10: epilogue-interleave in the persistent RNN step.
// Step restructured: kc=0..2 for all p (12 MFMA), then per-p
// {MFMA(kc=3,p); epilogue(p)} so epilogues of p=0..2 issue under the
// remaining MFMA issue; only the last p's epilogue is serial before the
// barrier. Pack kernels fused into one launch. All round-9 numerics kept.

typedef __attribute__((ext_vector_type(8))) int i32x8_t;
typedef __attribute__((ext_vector_type(4))) float f32x4_t;

constexpr int Bn = 256, Tn = 512, En = 100, Un = 512;
constexpr int D1n = 1024, D2n = 1024, Cn = 10;
constexpr float QS  = 256.f;               // quant scale 2^8
constexpr float INV = 1.52587890625e-05f;  // 2^-16
constexpr int USC = 0x7F7F7F7F;            // unit E8M0 scales (2^0)
constexpr int XW_STEP = 16 * 512 * 16;     // ushorts per t-slice (256 KB)

// ---- fp8 e4m3fn conversion helpers ----------------------------------------
__device__ __forceinline__ unsigned f2e4m3_sw(float x) {
    unsigned u = __float_as_uint(x);
    unsigned sgn = (u >> 24) & 0x80;
    float a = __uint_as_float(u & 0x7FFFFFFF);
    if (a >= 448.f) return sgn | 0x7E;
    if (a < 0.015625f) {
        unsigned q = (unsigned)__float2int_rn(a * 512.f);
        return sgn | q;
    }
    int e = (int)((u >> 23) & 0xFF) - 127;
    unsigned m = u & 0x7FFFFF;
    unsigned mant = m >> 20, rem = m & 0xFFFFF;
    if (rem > 0x80000 || (rem == 0x80000 && (mant & 1))) {
        if (++mant == 8) { mant = 0; ++e; }
    }
    if (e > 8) return sgn | 0x7E;
    return sgn | ((unsigned)(e + 7) << 3) | mant;
}

__device__ __forceinline__ unsigned cvt1(float x) {
#if __has_builtin(__builtin_amdgcn_cvt_pk_fp8_f32)
    return (unsigned)__builtin_amdgcn_cvt_pk_fp8_f32(x, x, 0, false) & 0xFFu;
#else
    return f2e4m3_sw(x);
#endif
}

__device__ __forceinline__ unsigned pk4(float a, float b, float c, float d) {
#if __has_builtin(__builtin_amdgcn_cvt_pk_fp8_f32)
    int r = __builtin_amdgcn_cvt_pk_fp8_f32(a, b, 0, false);
    r = __builtin_amdgcn_cvt_pk_fp8_f32(c, d, r, true);
    return (unsigned)r;
#else
    return f2e4m3_sw(a) | (f2e4m3_sw(b) << 8) | (f2e4m3_sw(c) << 16) |
           (f2e4m3_sw(d) << 24);
#endif
}

__device__ __forceinline__ ushort f2bf(float x) {
    unsigned u = __float_as_uint(x);
    unsigned r = (u + 0x7FFFu + ((u >> 16) & 1u)) >> 16;   // RNE
    return (ushort)r;
}

// relaxed barrier: LDS visibility only; vmcnt survives (T4)
__device__ __forceinline__ void lds_barrier() {
    asm volatile("s_waitcnt lgkmcnt(0)" ::: "memory");
    __builtin_amdgcn_s_barrier();
}

// ---------------------------------------------------------------------------
// Fused weight pack: Wh (262144 elems) then Wx (65536 elems), fp8 MX
// A-fragment order, scaled by QS.
// ---------------------------------------------------------------------------
__global__ __launch_bounds__(256) void pack_w8(
    const float* __restrict__ Wh, const float* __restrict__ Wx,
    unsigned char* __restrict__ PWh, unsigned char* __restrict__ PWx)
{
    int e = blockIdx.x * 256 + threadIdx.x;
    if (e < 262144) {
        int j = e & 31, l = (e >> 5) & 63, kc = (e >> 11) & 3, nt = e >> 13;
        int k = kc * 128 + (l >> 4) * 32 + j;
        int c = nt * 16 + (l & 15);
        PWh[e] = (unsigned char)cvt1(Wh[k * Un + c] * QS);
    } else {
        int e2 = e - 262144;                 // < 65536
        int j = e2 & 31, l = (e2 >> 5) & 63, nt = e2 >> 11;
        int k = (l >> 4) * 32 + j;
        int c = nt * 16 + (l & 15);
        PWx[e2] = (k < En) ? (unsigned char)cvt1(Wx[k * Un + c] * QS) : 0;
    }
}

// ---------------------------------------------------------------------------
// xw_gemm: xwp = bf16( (x_fp8 @ Wx_fp8)*INV + b_rnn ) -- TRUE value,
// per-thread-contiguous xwp[((t*16+blk)*512 + tid)*16 .. +16).
// ---------------------------------------------------------------------------
__global__ __launch_bounds__(512) void xw_gemm(
    const int* __restrict__ tokens, const float* __restrict__ emb,
    const float* __restrict__ b_rnn, const unsigned char* __restrict__ WxP8,
    ushort* __restrict__ xwp)
{
    __shared__ char XS[32768];       // 16 slabs of [16 rows][128 k] fp8

    const int tid  = threadIdx.x;
    const int lane = tid & 63;
    const int wv   = tid >> 6;
    const int r0   = blockIdx.x * 16;
    const int t0   = blockIdx.y * 16;

    const int r16 = lane & 15;
    const int q   = lane >> 4;

    for (int idx = tid; idx < 6400; idx += 512) {
        int tt   = idx / 400;
        int rem  = idx - tt * 400;
        int prow = rem / 25;
        int pc4  = rem - prow * 25;
        int tok  = tokens[(r0 + prow) * Tn + t0 + tt];
        float4 v = *(const float4*)(emb + tok * En + pc4 * 4);
        *(unsigned*)(XS + tt * 2048 + ((prow * 128 + pc4 * 4) ^ (prow << 4))) =
            pk4(v.x * QS, v.y * QS, v.z * QS, v.w * QS);
    }
    for (int idx = tid; idx < 16 * 16 * 7; idx += 512) {
        int tt   = idx / 112;
        int rem  = idx - tt * 112;
        int prow = rem / 7;
        int c4   = 25 + (rem - prow * 7);
        *(unsigned*)(XS + tt * 2048 + ((prow * 128 + c4 * 4) ^ (prow << 4))) = 0;
    }
    __syncthreads();

    i32x8_t wxf[4];
#pragma unroll
    for (int p = 0; p < 4; ++p)
        wxf[p] = *(const i32x8_t*)(WxP8 + ((wv * 4 + p) * 64 + lane) * 32);

    float bias_r[4][4];
#pragma unroll
    for (int p = 0; p < 4; ++p)
#pragma unroll
        for (int j = 0; j < 4; ++j)
            bias_r[p][j] = b_rnn[(wv * 4 + p) * 16 + q * 4 + j];

    const int bswz = r16 << 4;
    for (int tt = 0; tt < 16; ++tt) {
        uint4 blo = *(const uint4*)(XS + tt * 2048 +
                        ((r16 * 128 + q * 32) ^ bswz));
        uint4 bhi = *(const uint4*)(XS + tt * 2048 +
                        (((r16 * 128 + q * 32) + 16) ^ bswz));
        i32x8_t bf = {(int)blo.x, (int)blo.y, (int)blo.z, (int)blo.w,
                      (int)bhi.x, (int)bhi.y, (int)bhi.z, (int)bhi.w};
        f32x4_t acc[4];
#pragma unroll
        for (int p = 0; p < 4; ++p) {
            acc[p] = (f32x4_t){0.f, 0.f, 0.f, 0.f};
            acc[p] = __builtin_amdgcn_mfma_scale_f32_16x16x128_f8f6f4(
                wxf[p], bf, acc[p], 0, 0, 0, USC, 0, USC);
        }
        float v[4][4];
#pragma unroll
        for (int p = 0; p < 4; ++p)
#pragma unroll
            for (int j = 0; j < 4; ++j)
                v[p][j] = fmaf(acc[p][j], INV, bias_r[p][j]);

        size_t base = (((size_t)(t0 + tt) * 16 + blockIdx.x) * 512 + tid) * 16;
        uint4 lo, hi;
        lo.x = (unsigned)f2bf(v[0][0]) | ((unsigned)f2bf(v[0][1]) << 16);
        lo.y = (unsigned)f2bf(v[0][2]) | ((unsigned)f2bf(v[0][3]) << 16);
        lo.z = (unsigned)f2bf(v[1][0]) | ((unsigned)f2bf(v[1][1]) << 16);
        lo.w = (unsigned)f2bf(v[1][2]) | ((unsigned)f2bf(v[1][3]) << 16);
        hi.x = (unsigned)f2bf(v[2][0]) | ((unsigned)f2bf(v[2][1]) << 16);
        hi.y = (unsigned)f2bf(v[2][2]) | ((unsigned)f2bf(v[2][3]) << 16);
        hi.z = (unsigned)f2bf(v[3][0]) | ((unsigned)f2bf(v[3][1]) << 16);
        hi.w = (unsigned)f2bf(v[3][2]) | ((unsigned)f2bf(v[3][3]) << 16);
        *(uint4*)(xwp + base)     = lo;
        *(uint4*)(xwp + base + 8) = hi;
    }
}

// ---------------------------------------------------------------------------
// Slim persistent RNN. LDS: H0@0(8192) H1@8192 TOKM@16384(1KB) = 17.5 KB.
// Step = prefetch; 12 MFMA (kc 0..2); per-p {MFMA kc3; epilogue}; barrier.
// ---------------------------------------------------------------------------
__global__ __launch_bounds__(512, 2) void rnn_persist8x(
    const int* __restrict__ tokens, const unsigned char* __restrict__ WhP8,
    const ushort* __restrict__ xwp, float* __restrict__ h_final)
{
    __shared__ char sh[17408];
    char* H0 = sh;            char* H1 = sh + 8192;
    unsigned* TOKM = (unsigned*)(sh + 16384);

    const int tid  = threadIdx.x;
    const int lane = tid & 63;
    const int wv   = tid >> 6;
    const int r0   = blockIdx.x * 16;

    const int r16  = lane & 15;
    const int q    = lane >> 4;
    const int bswz = r16 << 4;

    if (tid < 256) {
        int row = tid >> 4, ch = tid & 15;
        const int* tp = tokens + (r0 + row) * Tn + ch * 32;
        unsigned m = 0;
#pragma unroll
        for (int i = 0; i < 32; ++i) m |= (tp[i] != 0 ? 1u : 0u) << i;
        TOKM[row * 16 + ch] = m;
    }
    {   // zero H0
        int* z = (int*)sh;
        for (int f = tid; f < 2048; f += 512) z[f] = 0;
    }
    __syncthreads();

    i32x8_t whf[4][4];
#pragma unroll
    for (int kc = 0; kc < 4; ++kc)
#pragma unroll
        for (int p = 0; p < 4; ++p)
            whf[kc][p] = *(const i32x8_t*)(WhP8 +
                (((wv * 4 + p) * 4 + kc) * 64 + lane) * 32);

    const ushort* xwT = xwp + ((size_t)blockIdx.x * 512 + tid) * 16;
    const ushort* xnext = xwT + XW_STEP;

    float hprev[4][4];
#pragma unroll
    for (int p = 0; p < 4; ++p)
#pragma unroll
        for (int j = 0; j < 4; ++j) hprev[p][j] = 0.f;

    uint4 pfA0 = *(const uint4*)(xwT);
    uint4 pfA1 = *(const uint4*)(xwT + 8);
    uint4 pfB0, pfB1;

#define BFL(u) __uint_as_float((u) << 16)
#define BFH(u) __uint_as_float((u) & 0xFFFF0000u)

#define EPI(P, ACC, WLO, WHI, MK)                                              \
    {                                                                          \
        float v0 = fmaxf(fmaf((ACC)[0], INV, BFL(WLO)), 0.f);                  \
        float v1 = fmaxf(fmaf((ACC)[1], INV, BFH(WLO)), 0.f);                  \
        float v2 = fmaxf(fmaf((ACC)[2], INV, BFL(WHI)), 0.f);                  \
        float v3 = fmaxf(fmaf((ACC)[3], INV, BFH(WHI)), 0.f);                  \
        v0 = (MK) ? v0 : hprev[P][0];  v1 = (MK) ? v1 : hprev[P][1];           \
        v2 = (MK) ? v2 : hprev[P][2];  v3 = (MK) ? v3 : hprev[P][3];           \
        hprev[P][0] = v0; hprev[P][1] = v1;                                    \
        hprev[P][2] = v2; hprev[P][3] = v3;                                    \
        *(unsigned*)((HN_) +                                                   \
            ((r16 * 512 + (wv * 4 + (P)) * 16 + q * 4) ^ bswz)) =              \
            pk4(v0 * QS, v1 * QS, v2 * QS, v3 * QS);                           \
    }

#define RNN_STEP(HC, HN, C0, C1, N0, N1, MK)                                   \
    {                                                                          \
        char* HN_ = (HN);                                                      \
        N0 = *(const uint4*)(xnext);                                           \
        N1 = *(const uint4*)(xnext + 8);                                       \
        xnext += XW_STEP;                                                      \
        f32x4_t acc[4];                                                        \
        _Pragma("unroll")                                                      \
        for (int p = 0; p < 4; ++p) acc[p] = (f32x4_t){0.f, 0.f, 0.f, 0.f};    \
        /* kc = 0..2: all p */                                                 \
        _Pragma("unroll")                                                      \
        for (int kc = 0; kc < 3; ++kc) {                                       \
            const int bb = r16 * 512 + kc * 128 + q * 32;                      \
            uint4 blo = *(const uint4*)((HC) + ((bb) ^ bswz));                 \
            uint4 bhi = *(const uint4*)((HC) + ((bb + 16) ^ bswz));            \
            i32x8_t bf = {(int)blo.x, (int)blo.y, (int)blo.z, (int)blo.w,      \
                          (int)bhi.x, (int)bhi.y, (int)bhi.z, (int)bhi.w};     \
            _Pragma("unroll")                                                  \
            for (int p = 0; p < 4; ++p)                                        \
                acc[p] = __builtin_amdgcn_mfma_scale_f32_16x16x128_f8f6f4(     \
                    whf[kc][p], bf, acc[p], 0, 0, 0, USC, 0, USC);             \
        }                                                                      \
        /* kc = 3: per-p MFMA immediately followed by that p's epilogue */     \
        const bool mk = (MK);                                                  \
        {                                                                      \
            const int bb = r16 * 512 + 3 * 128 + q * 32;                       \
            uint4 blo = *(const uint4*)((HC) + ((bb) ^ bswz));                 \
            uint4 bhi = *(const uint4*)((HC) + ((bb + 16) ^ bswz));            \
            i32x8_t bf = {(int)blo.x, (int)blo.y, (int)blo.z, (int)blo.w,      \
                          (int)bhi.x, (int)bhi.y, (int)bhi.z, (int)bhi.w};     \
            acc[0] = __builtin_amdgcn_mfma_scale_f32_16x16x128_f8f6f4(         \
                whf[3][0], bf, acc[0], 0, 0, 0, USC, 0, USC);                  \
            EPI(0, acc[0], C0.x, C0.y, mk)                                     \
            acc[1] = __builtin_amdgcn_mfma_scale_f32_16x16x128_f8f6f4(         \
                whf[3][1], bf, acc[1], 0, 0, 0, USC, 0, USC);                  \
            EPI(1, acc[1], C0.z, C0.w, mk)                                     \
            acc[2] = __builtin_amdgcn_mfma_scale_f32_16x16x128_f8f6f4(         \
                whf[3][2], bf, acc[2], 0, 0, 0, USC, 0, USC);                  \
            EPI(2, acc[2], C1.x, C1.y, mk)                                     \
            acc[3] = __builtin_amdgcn_mfma_scale_f32_16x16x128_f8f6f4(         \
                whf[3][3], bf, acc[3], 0, 0, 0, USC, 0, USC);                  \
            EPI(3, acc[3], C1.z, C1.w, mk)                                     \
        }                                                                      \
        lds_barrier();                                                         \
    }

    const unsigned* mrow = TOKM + r16 * 16;
    for (int tc = 0; tc < 16; ++tc) {
        unsigned m32 = mrow[tc];
        for (int ii = 0; ii < 16; ++ii) {
            RNN_STEP(H0, H1, pfA0, pfA1, pfB0, pfB1, (m32 & 1u) != 0) m32 >>= 1;
            RNN_STEP(H1, H0, pfB0, pfB1, pfA0, pfA1, (m32 & 1u) != 0) m32 >>= 1;
        }
    }
#undef RNN_STEP
#undef EPI
#undef BFL
#undef BFH

#pragma unroll
    for (int p = 0; p < 4; ++p) {
        int n = (wv * 4 + p) * 16 + q * 4;
#pragma unroll
        for (int j = 0; j < 4; ++j)
            h_final[(r0 + r16) * Un + n + j] = hprev[p][j];
    }
}

// ---------------------------------------------------------------------------
// Fallback: round-5 persistent kernel (in-loop x@Wx), used when ws is small.
// ---------------------------------------------------------------------------
__global__ __launch_bounds__(512, 2) void rnn_persist8(
    const int* __restrict__ tokens, const float* __restrict__ emb,
    const float* __restrict__ b_rnn,
    const unsigned char* __restrict__ WhP8, const unsigned char* __restrict__ WxP8,
    float* __restrict__ h_final)
{
    __shared__ char sh[36864];
    char* H0 = sh;            char* H1 = sh + 8192;
    char* X0 = sh + 16384;    char* X1 = sh + 18432;
    char* TOKB = sh + 20480;

    const int tid  = threadIdx.x;
    const int lane = tid & 63;
    const int wv   = tid >> 6;
    const int r0   = blockIdx.x * 16;

    const int r16  = lane & 15;
    const int q    = lane >> 4;
    const int bswz = r16 << 4;

    for (int f = tid; f < 16 * Tn; f += 512) {
        int row = f >> 9, tt = f & 511;
        *(ushort*)(TOKB + ((((row << 10) | (tt << 1))) ^ (row << 2))) =
            (ushort)tokens[r0 * Tn + f];
    }
    {
        int* z = (int*)sh;
        for (int f = tid; f < 2048; f += 512) z[f] = 0;
        int* zx = (int*)(sh + 16384);
        for (int f = tid; f < 1024; f += 512) zx[f] = 0;
    }
    __syncthreads();

    i32x8_t whf[4][4], wxf[4];
#pragma unroll
    for (int kc = 0; kc < 4; ++kc)
#pragma unroll
        for (int p = 0; p < 4; ++p)
            whf[kc][p] = *(const i32x8_t*)(WhP8 +
                (((wv * 4 + p) * 4 + kc) * 64 + lane) * 32);
#pragma unroll
    for (int p = 0; p < 4; ++p)
        wxf[p] = *(const i32x8_t*)(WxP8 + ((wv * 4 + p) * 64 + lane) * 32);

    float bias_r[4][4];
#pragma unroll
    for (int p = 0; p < 4; ++p)
#pragma unroll
        for (int j = 0; j < 4; ++j)
            bias_r[p][j] = b_rnn[(wv * 4 + p) * 16 + q * 4 + j];

    const int prow = tid / 25;
    const int pc4  = tid - prow * 25;
    const bool is_pref = (tid < 400);
    const int pxaddr = (prow * 128 + pc4 * 4) ^ (prow << 4);

    if (is_pref) {
        int tk = (int)*(const ushort*)(TOKB + (((prow << 10)) ^ (prow << 2)));
        float4 v = *(const float4*)(emb + tk * En + pc4 * 4);
        *(unsigned*)(X0 + pxaddr) = pk4(v.x * QS, v.y * QS, v.z * QS, v.w * QS);
    }
    __syncthreads();

    float hprev[4][4];
#pragma unroll
    for (int p = 0; p < 4; ++p)
#pragma unroll
        for (int j = 0; j < 4; ++j) hprev[p][j] = 0.f;

#define RNN_STEP(T, HC, HN, XC, XN)                                            \
    {                                                                          \
        const int t = (T);                                                     \
        float4 pref;                                                           \
        const bool dp = is_pref && (t + 1 < Tn);                               \
        if (dp) {                                                              \
            int tk = (int)*(const ushort*)(TOKB +                              \
                ((((prow << 10) | ((t + 1) << 1))) ^ (prow << 2)));            \
            pref = *(const float4*)(emb + tk * En + pc4 * 4);                  \
        }                                                                      \
        f32x4_t acc[4];                                                        \
        _Pragma("unroll")                                                      \
        for (int p = 0; p < 4; ++p) acc[p] = (f32x4_t){0.f, 0.f, 0.f, 0.f};    \
        _Pragma("unroll")                                                      \
        for (int kc = 0; kc < 4; ++kc) {                                       \
            const int bb = r16 * 512 + kc * 128 + q * 32;                      \
            uint4 blo = *(const uint4*)((HC) + ((bb) ^ bswz));                 \
            uint4 bhi = *(const uint4*)((HC) + ((bb + 16) ^ bswz));            \
            i32x8_t bf = {(int)blo.x, (int)blo.y, (int)blo.z, (int)blo.w,      \
                          (int)bhi.x, (int)bhi.y, (int)bhi.z, (int)bhi.w};     \
            _Pragma("unroll")                                                  \
            for (int p = 0; p < 4; ++p)                                        \
                acc[p] = __builtin_amdgcn_mfma_scale_f32_16x16x128_f8f6f4(     \
                    whf[kc][p], bf, acc[p], 0, 0, 0, USC, 0, USC);             \
        }                                                                      \
        {                                                                      \
            const int xb = r16 * 128 + q * 32;                                 \
            uint4 blo = *(const uint4*)((XC) + ((xb) ^ bswz));                 \
            uint4 bhi = *(const uint4*)((XC) + ((xb + 16) ^ bswz));            \
            i32x8_t bf = {(int)blo.x, (int)blo.y, (int)blo.z, (int)blo.w,      \
                          (int)bhi.x, (int)bhi.y, (int)bhi.z, (int)bhi.w};     \
            _Pragma("unroll")                                                  \
            for (int p = 0; p < 4; ++p)                                        \
                acc[p] = __builtin_amdgcn_mfma_scale_f32_16x16x128_f8f6f4(     \
                    wxf[p], bf, acc[p], 0, 0, 0, USC, 0, USC);                 \
        }                                                                      \
        const bool mk = *(const ushort*)(TOKB +                                \
            ((((r16 << 10) | (t << 1))) ^ (r16 << 2))) != 0;                   \
        _Pragma("unroll")                                                      \
        for (int p = 0; p < 4; ++p) {                                          \
            float v0 = fmaxf(acc[p][0] * INV + bias_r[p][0], 0.f);             \
            float v1 = fmaxf(acc[p][1] * INV + bias_r[p][1], 0.f);             \
            float v2 = fmaxf(acc[p][2] * INV + bias_r[p][2], 0.f);             \
            float v3 = fmaxf(acc[p][3] * INV + bias_r[p][3], 0.f);             \
            v0 = mk ? v0 : hprev[p][0];  v1 = mk ? v1 : hprev[p][1];           \
            v2 = mk ? v2 : hprev[p][2];  v3 = mk ? v3 : hprev[p][3];           \
            hprev[p][0] = v0; hprev[p][1] = v1;                                \
            hprev[p][2] = v2; hprev[p][3] = v3;                                \
            *(unsigned*)((HN) +                                                \
                ((r16 * 512 + (wv * 4 + p) * 16 + q * 4) ^ bswz)) =            \
                pk4(v0 * QS, v1 * QS, v2 * QS, v3 * QS);                       \
        }                                                                      \
        if (dp) {                                                              \
            *(unsigned*)((XN) + pxaddr) =                                      \
                pk4(pref.x * QS, pref.y * QS, pref.z * QS, pref.w * QS);       \
        }                                                                      \
        __syncthreads();                                                       \
    }

    for (int t2 = 0; t2 < Tn; t2 += 2) {
        RNN_STEP(t2,     H0, H1, X0, X1)
        RNN_STEP(t2 + 1, H1, H0, X1, X0)
    }
#undef RNN_STEP

#pragma unroll
    for (int p = 0; p < 4; ++p) {
        int n = (wv * 4 + p) * 16 + q * 4;
#pragma unroll
        for (int j = 0; j < 4; ++j)
            h_final[(r0 + r16) * Un + n + j] = hprev[p][j];
    }
}

// ---------------------------------------------------------------------------
// MLP: 32-row tiles, K staged in 512-chunks (64 KB LDS).
// ---------------------------------------------------------------------------
template <int K, bool RELU>
__global__ __launch_bounds__(256) void fc32(
    const float* __restrict__ in, const float* __restrict__ W,
    const float* __restrict__ b, float* __restrict__ out, int N)
{
    __shared__ float in_lds[32][512];
    const int tid = threadIdx.x;
    const int r0  = blockIdx.y * 32;
    const int c0  = blockIdx.x * 32;

    const int col = c0 + (tid & 31);
    const int rq  = (tid >> 5) * 4;     // 4 rows per thread

    float acc0 = b[col], acc1 = acc0, acc2 = acc0, acc3 = acc0;

    for (int kc = 0; kc < K / 512; ++kc) {
        if (kc) __syncthreads();
        for (int i = tid; i < 32 * 512; i += 256) {
            int r = i >> 9, c = i & 511;
            in_lds[r][c] = in[(r0 + r) * K + kc * 512 + c];
        }
        __syncthreads();

        const float4* v0 = (const float4*)(&in_lds[rq + 0][0]);
        const float4* v1 = (const float4*)(&in_lds[rq + 1][0]);
        const float4* v2 = (const float4*)(&in_lds[rq + 2][0]);
        const float4* v3 = (const float4*)(&in_lds[rq + 3][0]);
        for (int k4 = 0; k4 < 128; ++k4) {
            float4 a0 = v0[k4], a1 = v1[k4], a2 = v2[k4], a3 = v3[k4];
            int k = kc * 512 + k4 * 4;
            float w0 = W[(k + 0) * N + col];
            float w1 = W[(k + 1) * N + col];
            float w2 = W[(k + 2) * N + col];
            float w3 = W[(k + 3) * N + col];
            acc0 += a0.x * w0 + a0.y * w1 + a0.z * w2 + a0.w * w3;
            acc1 += a1.x * w0 + a1.y * w1 + a1.z * w2 + a1.w * w3;
            acc2 += a2.x * w0 + a2.y * w1 + a2.z * w2 + a2.w * w3;
            acc3 += a3.x * w0 + a3.y * w1 + a3.z * w2 + a3.w * w3;
        }
    }
    if (RELU) {
        acc0 = fmaxf(acc0, 0.f); acc1 = fmaxf(acc1, 0.f);
        acc2 = fmaxf(acc2, 0.f); acc3 = fmaxf(acc3, 0.f);
    }
    out[(r0 + rq + 0) * N + col] = acc0;
    out[(r0 + rq + 1) * N + col] = acc1;
    out[(r0 + rq + 2) * N + col] = acc2;
    out[(r0 + rq + 3) * N + col] = acc3;
}

__global__ __launch_bounds__(64) void head_softmax(
    const float* __restrict__ h2, const float* __restrict__ Wo,
    const float* __restrict__ bo, float* __restrict__ out)
{
    const int b    = blockIdx.x;
    const int lane = threadIdx.x;

    float acc[Cn];
#pragma unroll
    for (int c = 0; c < Cn; ++c) acc[c] = 0.f;

    for (int k = lane; k < D2n; k += 64) {
        float hv = h2[b * D2n + k];
#pragma unroll
        for (int c = 0; c < Cn; ++c) acc[c] += hv * Wo[k * Cn + c];
    }
#pragma unroll
    for (int c = 0; c < Cn; ++c) {
#pragma unroll
        for (int off = 32; off > 0; off >>= 1)
            acc[c] += __shfl_down(acc[c], off);
    }
    if (lane == 0) {
        float l[Cn], mx = -1e30f;
#pragma unroll
        for (int c = 0; c < Cn; ++c) { l[c] = acc[c] + bo[c]; mx = fmaxf(mx, l[c]); }
        float s = 0.f;
#pragma unroll
        for (int c = 0; c < Cn; ++c) { l[c] = __expf(l[c] - mx); s += l[c]; }
        float inv = 1.f / s;
#pragma unroll
        for (int c = 0; c < Cn; ++c) out[b * Cn + c] = l[c] * inv;
    }
}

extern "C" void kernel_launch(void* const* d_in, const int* in_sizes, int n_in,
                              void* d_out, int out_size, void* d_ws, size_t ws_size,
                              hipStream_t stream)
{
    const int*   tokens = (const int*)d_in[0];
    const float* emb    = (const float*)d_in[1];
    const float* Wx     = (const float*)d_in[2];
    const float* Wh     = (const float*)d_in[3];
    const float* b_rnn  = (const float*)d_in[4];
    const float* W1     = (const float*)d_in[5];
    const float* b1     = (const float*)d_in[6];
    const float* W2     = (const float*)d_in[7];
    const float* b2     = (const float*)d_in[8];
    const float* Wo     = (const float*)d_in[9];
    const float* bo     = (const float*)d_in[10];
    float* out = (float*)d_out;

    char* ws = (char*)d_ws;
    unsigned char* WhP8 = (unsigned char*)ws;                 // 256 KB
    unsigned char* WxP8 = (unsigned char*)(ws + (256 << 10)); // 64 KB
    float* h_last = (float*)(ws + (320 << 10));               // 512 KB
    float* h1     = (float*)(ws + (832 << 10));               // 1 MB
    float* h2     = (float*)(ws + (1856 << 10));              // 1 MB
    ushort* xwp   = (ushort*)(ws + (3u << 20));               // 128.25 MB
    const size_t need = (3u << 20) +
        (size_t)(Tn + 1) * XW_STEP * sizeof(ushort);

    pack_w8<<<1280, 256, 0, stream>>>(Wh, Wx, WhP8, WxP8);

    if (ws_size >= need) {
        xw_gemm<<<dim3(16, 32), 512, 0, stream>>>(tokens, emb, b_rnn, WxP8, xwp);
        rnn_persist8x<<<Bn / 16, 512, 0, stream>>>(tokens, WhP8, xwp, h_last);
    } else {
        rnn_persist8<<<Bn / 16, 512, 0, stream>>>(
            tokens, emb, b_rnn, WhP8, WxP8, h_last);
    }

    dim3 bs(256);
    fc32<Un, true><<<dim3(D1n / 32, Bn / 32), bs, 0, stream>>>(h_last, W1, b1, h1, D1n);
    fc32<D1n, true><<<dim3(D2n / 32, Bn / 32), bs, 0, stream>>>(h1, W2, b2, h2, D2n);
    head_softmax<<<Bn, 64, 0, stream>>>(h2, Wo, bo, out);
}